// Round 1
// 645.956 us; speedup vs baseline: 1.1637x; 1.1637x over previous
//
#include <hip/hip_runtime.h>
#include <math.h>

// ---------------------------------------------------------------------------
// LinearNO block, MI355X/gfx950. Inputs fp32 (sniffed; bf16 fallback).
// Interior bf16 MFMA. B=8 N=8192 C=256 H=8 D=32 S=32.
//
// R8 changes vs R7 (751 us):
//  * gemm_bt: 3-deep LDS ring pipeline (stage t+2 while computing t) with
//    counted s_waitcnt vmcnt(8/4/0) + raw s_barrier (no __syncthreads drain).
//  * gemm_bt / gemm_bt_ln / gemm_w2out: epilogue stages the f32 accumulator
//    tile through LDS and stores coalesced u16x8 / f32x4 rows (was 2B/4B
//    scattered stores at 512B stride). Residual read coalesced in same pass.
//  * segment softmax fused into gemm_bt epilogue (act=3); softmax_seg gone.
//  * gemm_w2out: 4-deep ring (grid is 1 block/CU -> needs deepest pipeline).
// ---------------------------------------------------------------------------

typedef __attribute__((ext_vector_type(8))) short bf8;
typedef __attribute__((ext_vector_type(4))) float f32x4;
typedef __attribute__((ext_vector_type(4))) unsigned short u16x4;
typedef __attribute__((ext_vector_type(8))) unsigned short u16x8;

__device__ __forceinline__ float b2f(unsigned short x) {
  union { unsigned u; float f; } t; t.u = ((unsigned)x) << 16; return t.f;
}
__device__ __forceinline__ unsigned short f2b(float f) {
  union { float f; unsigned u; } t; t.f = f;
  unsigned r = t.u + 0x7fffu + ((t.u >> 16) & 1u);
  return (unsigned short)(r >> 16);
}
__device__ __forceinline__ float gelu_exact(float x) {
  return 0.5f * x * (1.0f + erff(x * 0.7071067811865475f));
}

// async global->LDS, 16 B per lane. LDS dest must be base + lane*16.
typedef __attribute__((address_space(1))) const void gas_void;
typedef __attribute__((address_space(3))) void las_void;
__device__ __forceinline__ void gl_lds16(const void* g, void* l) {
  __builtin_amdgcn_global_load_lds((gas_void*)g, (las_void*)l, 16, 0, 0);
}

// --------------------------- dtype sniffer ---------------------------------
__global__ void sniff_kernel(const unsigned* __restrict__ fx, int* __restrict__ flag) {
  if (threadIdx.x == 0) {
    int cnt = 0;
    for (int i = 0; i < 64; i++) {
      unsigned e = (fx[i] >> 7) & 0xFFu;
      cnt += (e >= 117u && e <= 130u) ? 1 : 0;
    }
    *flag = (cnt >= 32) ? 1 : 0;   // 1 = bf16 inputs, 0 = fp32
  }
}

// --------------------------- weight table ----------------------------------
struct CvtDesc { const void* src[15]; int off[15]; int n[15]; };

__global__ __launch_bounds__(256) void cvt_tab(CvtDesc d, unsigned short* __restrict__ wtab,
                                               const int* __restrict__ flagp) {
  const int seg = blockIdx.y;
  const int i = blockIdx.x * 256 + threadIdx.x;
  if (i >= d.n[seg]) return;
  unsigned short o;
  if (*flagp) o = ((const unsigned short*)d.src[seg])[i];
  else        o = f2b(((const float*)d.src[seg])[i]);
  wtab[d.off[seg] + i] = o;
}

// Block-diagonal Wq_big / Wk_big [256,256]: big[h*32+s][h*32+d]=W[s][d].
__global__ __launch_bounds__(256) void build_big(
    const unsigned short* __restrict__ wq, const unsigned short* __restrict__ wk,
    unsigned short* __restrict__ Wqbig, unsigned short* __restrict__ Wkbig)
{
  const int idx = blockIdx.x * 256 + threadIdx.x;
  const int row = idx >> 8, col = idx & 255;
  const bool same = (row >> 5) == (col >> 5);
  const int wi = (row & 31) * 32 + (col & 31);
  Wqbig[idx] = same ? wq[wi] : (unsigned short)0;
  Wkbig[idx] = same ? wk[wi] : (unsigned short)0;
}

__global__ __launch_bounds__(256) void zero_u16(unsigned short* __restrict__ p, int n) {
  int i8 = (blockIdx.x * 256 + threadIdx.x) * 8;
  if (i8 < n) { u16x8 z = {}; *(u16x8*)&p[i8] = z; }
}

// --------------------------- LN stats --------------------------------------
__global__ __launch_bounds__(256) void ln_stats(
    const void* __restrict__ X, const int* __restrict__ flagp, int amode,
    float* __restrict__ MU, float* __restrict__ RS)
{
  const int lane = threadIdx.x & 63;
  const int wave = threadIdx.x >> 6;
  const size_t row = (size_t)blockIdx.x * 4 + wave;
  const size_t base = row * 256 + lane * 4;
  const bool abf = amode ? ((*flagp) != 0) : true;
  float x0, x1, x2, x3;
  if (abf) {
    u16x4 uv = *(const u16x4*)&((const unsigned short*)X)[base];
    x0 = b2f(uv[0]); x1 = b2f(uv[1]); x2 = b2f(uv[2]); x3 = b2f(uv[3]);
  } else {
    f32x4 t = *(const f32x4*)&((const float*)X)[base];
    x0 = t[0]; x1 = t[1]; x2 = t[2]; x3 = t[3];
  }
  float s = x0 + x1 + x2 + x3;
  float q = x0*x0 + x1*x1 + x2*x2 + x3*x3;
  #pragma unroll
  for (int m = 1; m < 64; m <<= 1) { s += __shfl_xor(s, m, 64); q += __shfl_xor(q, m, 64); }
  float mean = s * (1.0f / 256.0f);
  float var  = q * (1.0f / 256.0f) - mean * mean;
  if (lane == 0) { MU[row] = mean; RS[row] = rsqrtf(var + 1e-5f); }
}

// --------------------------- generic MFMA GEMM (pipelined) ------------------
// Y[.,N] = A @ W^T + bias (+Res dtype-branched) ; act: 0 none, 2 exp,
// 3 segment-softmax (32-col segments, fused jax.nn.softmax over slices).
// 128x128 tile; 3-slot LDS ring, stage t+2 while computing t, counted vmcnt.
// z-batch: rows += z*mz, W += z*wz.
__global__ __launch_bounds__(256) void gemm_bt(
    const unsigned short* __restrict__ A,
    const unsigned short* __restrict__ W,
    const unsigned short* __restrict__ bias,
    const void* __restrict__ Res, const int* __restrict__ flagp,
    unsigned short* __restrict__ Y,
    int N, int K, int act, int mz, long wz)
{
  __shared__ __align__(16) unsigned short smem[3 * 8192];   // 48 KB ring
  const int tid = threadIdx.x, lane = tid & 63, wave = tid >> 6;
  const size_t zrow = (size_t)blockIdx.z * mz;
  const int bm = blockIdx.x * 128, bn = blockIdx.y * 128;
  const int wm = (wave >> 1) * 64, wn = (wave & 1) * 64;
  const int quad = lane >> 4, l16 = lane & 15;
  const unsigned short* Wz = W + (size_t)blockIdx.z * wz;

  f32x4 acc[4][4] = {};
  const int r0 = tid >> 2;
  const int co = (tid & 3) * 8;
  const unsigned short* pa0 = &A[(zrow + bm + r0) * K + co];
  const unsigned short* pa1 = &A[(zrow + bm + r0 + 64) * K + co];
  const unsigned short* pb0 = &Wz[(size_t)(bn + r0) * K + co];
  const unsigned short* pb1 = &Wz[(size_t)(bn + r0 + 64) * K + co];
  const int nt = K >> 5;

  auto stage = [&](int t, int sl) {
    const int k0 = t << 5;
    unsigned short* b_ = &smem[sl * 8192 + tid * 8];
    gl_lds16(pa0 + k0, b_);
    gl_lds16(pa1 + k0, b_ + 2048);
    gl_lds16(pb0 + k0, b_ + 4096);
    gl_lds16(pb1 + k0, b_ + 6144);
  };

  stage(0, 0);
  if (nt > 1) stage(1, 1);
  int scur = 0, snew = 2;
  for (int t = 0; t < nt; ++t) {
    if (t + 2 < nt) {
      stage(t + 2, snew);
      asm volatile("s_waitcnt vmcnt(8)" ::: "memory");   // tile t landed (mine)
    } else if (t + 1 < nt) {
      asm volatile("s_waitcnt vmcnt(4)" ::: "memory");
    } else {
      asm volatile("s_waitcnt vmcnt(0)" ::: "memory");
    }
    __builtin_amdgcn_s_barrier();                        // tile t landed (all)
    __builtin_amdgcn_sched_barrier(0);

    const unsigned short* sa = &smem[scur * 8192];
    const unsigned short* sb = sa + 4096;
    bf8 af[4], bfr[4];
    #pragma unroll
    for (int i = 0; i < 4; i++) af[i]  = *(const bf8*)&sa[(wm + i * 16 + l16) * 32 + quad * 8];
    #pragma unroll
    for (int j = 0; j < 4; j++) bfr[j] = *(const bf8*)&sb[(wn + j * 16 + l16) * 32 + quad * 8];
    #pragma unroll
    for (int i = 0; i < 4; i++)
      #pragma unroll
      for (int j = 0; j < 4; j++)
        acc[i][j] = __builtin_amdgcn_mfma_f32_16x16x32_bf16(af[i], bfr[j], acc[i][j], 0, 0, 0);

    __builtin_amdgcn_sched_barrier(0);
    __builtin_amdgcn_s_barrier();                        // all waves done reading slot
    scur = scur + 1 < 3 ? scur + 1 : 0;
    snew = snew + 1 < 3 ? snew + 1 : 0;
  }

  // ---- epilogue: bias/act in registers, f32 tile via LDS, coalesced stores
  const bool rbf = Res ? ((*flagp) != 0) : true;
  float bv[4];
  #pragma unroll
  for (int j = 0; j < 4; j++) bv[j] = b2f(bias[bn + wn + j * 16 + l16]);
  #pragma unroll
  for (int i = 0; i < 4; i++)
    #pragma unroll
    for (int j = 0; j < 4; j++)
      #pragma unroll
      for (int r = 0; r < 4; r++) {
        float v = acc[i][j][r] + bv[j];
        if (act == 2) v = __expf(v);
        acc[i][j][r] = v;
      }
  if (act == 3) {
    // softmax over 32-col segments: cols (wn + 2g*16 .. +31) live in j={2g,2g+1}
    // across the 16 lanes of this quad group.
    #pragma unroll
    for (int i = 0; i < 4; i++)
      #pragma unroll
      for (int g = 0; g < 2; g++)
        #pragma unroll
        for (int r = 0; r < 4; r++) {
          float a0 = acc[i][2*g][r], a1 = acc[i][2*g+1][r];
          float m = fmaxf(a0, a1);
          #pragma unroll
          for (int msk = 1; msk < 16; msk <<= 1) m = fmaxf(m, __shfl_xor(m, msk, 64));
          float e0 = __expf(a0 - m), e1 = __expf(a1 - m);
          float s = e0 + e1;
          #pragma unroll
          for (int msk = 1; msk < 16; msk <<= 1) s += __shfl_xor(s, msk, 64);
          const float rz = 1.0f / s;
          acc[i][2*g][r] = e0 * rz; acc[i][2*g+1][r] = e1 * rz;
        }
  }

  float* cf = (float*)smem;              // 64x128 f32 half-tile (32 KB)
  const int whalf = wm >> 6;
  #pragma unroll
  for (int half = 0; half < 2; ++half) {
    __builtin_amdgcn_s_barrier();
    if (whalf == half) {
      #pragma unroll
      for (int i = 0; i < 4; i++)
        #pragma unroll
        for (int j = 0; j < 4; j++)
          #pragma unroll
          for (int r = 0; r < 4; r++)
            cf[(i * 16 + quad * 4 + r) * 128 + wn + j * 16 + l16] = acc[i][j][r];
    }
    __builtin_amdgcn_s_barrier();
    #pragma unroll
    for (int st = 0; st < 4; ++st) {
      const int e = st * 2048 + tid * 8;
      const int row = e >> 7;
      const size_t gbase = (zrow + bm + half * 64 + row) * (size_t)N + bn + (e & 127);
      float v[8];
      #pragma unroll
      for (int u = 0; u < 8; u++) v[u] = cf[e + u];
      if (Res) {
        if (rbf) {
          u16x8 rv = *(const u16x8*)&((const unsigned short*)Res)[gbase];
          #pragma unroll
          for (int u = 0; u < 8; u++) v[u] += b2f(rv[u]);
        } else {
          f32x4 ra = *(const f32x4*)&((const float*)Res)[gbase];
          f32x4 rb = *(const f32x4*)&((const float*)Res)[gbase + 4];
          v[0] += ra[0]; v[1] += ra[1]; v[2] += ra[2]; v[3] += ra[3];
          v[4] += rb[0]; v[5] += rb[1]; v[6] += rb[2]; v[7] += rb[3];
        }
      }
      u16x8 o;
      #pragma unroll
      for (int u = 0; u < 8; u++) o[u] = f2b(v[u]);
      *(u16x8*)&Y[gbase] = o;
    }
  }
}

// GEMM with LN applied to A during staging (amode: 1=flag dtype, 0=bf16);
// B side uses DMA staging. act=1 -> GELU. Coalesced LDS epilogue.
__global__ __launch_bounds__(256) void gemm_bt_ln(
    const void* __restrict__ A, const int* __restrict__ flagp, int amode,
    const float* __restrict__ MU, const float* __restrict__ RS,
    const unsigned short* __restrict__ lw, const unsigned short* __restrict__ lb,
    const unsigned short* __restrict__ W, const unsigned short* __restrict__ bias,
    unsigned short* __restrict__ Y, int N, int K, int act)
{
  __shared__ __align__(16) unsigned char smemc[32768];       // lA+lB, cf overlay
  unsigned short* lA = (unsigned short*)smemc;
  unsigned short* lB = lA + 4096;
  const int tid = threadIdx.x, lane = tid & 63, wave = tid >> 6;
  const int bm = blockIdx.x * 128, bn = blockIdx.y * 128;
  const int wm = (wave >> 1) * 64, wn = (wave & 1) * 64;
  const int quad = lane >> 4, l16 = lane & 15;
  const bool abf = amode ? ((*flagp) != 0) : true;
  const unsigned short* Ab = (const unsigned short*)A;
  const float* Af = (const float*)A;

  f32x4 acc[4][4] = {};
  const int r0 = tid >> 2;
  const int co = (tid & 3) * 8;
  const unsigned short* pb0 = &W[(size_t)(bn + r0) * K + co];
  const unsigned short* pb1 = &W[(size_t)(bn + r0 + 64) * K + co];

  for (int k0 = 0; k0 < K; k0 += 32) {
    u16x8 wv8 = *(const u16x8*)&lw[k0 + co];
    u16x8 bv8 = *(const u16x8*)&lb[k0 + co];
    __syncthreads();
    gl_lds16(pb0 + k0, &lB[tid * 8]);
    gl_lds16(pb1 + k0, &lB[2048 + tid * 8]);
    #pragma unroll
    for (int half = 0; half < 2; half++) {
      const int ar = bm + r0 + half * 64;
      const float m_ = MU[ar], r_ = RS[ar];
      float xv[8];
      if (abf) {
        u16x8 t = *(const u16x8*)&Ab[(size_t)ar * K + k0 + co];
        #pragma unroll
        for (int e = 0; e < 8; e++) xv[e] = b2f(t[e]);
      } else {
        f32x4 t0 = *(const f32x4*)&Af[(size_t)ar * K + k0 + co];
        f32x4 t1 = *(const f32x4*)&Af[(size_t)ar * K + k0 + co + 4];
        xv[0]=t0[0]; xv[1]=t0[1]; xv[2]=t0[2]; xv[3]=t0[3];
        xv[4]=t1[0]; xv[5]=t1[1]; xv[6]=t1[2]; xv[7]=t1[3];
      }
      u16x8 o;
      #pragma unroll
      for (int e = 0; e < 8; e++)
        o[e] = f2b((xv[e] - m_) * r_ * b2f(wv8[e]) + b2f(bv8[e]));
      *(u16x8*)&lA[half * 2048 + tid * 8] = o;
    }
    __syncthreads();

    bf8 af[4], bfr[4];
    #pragma unroll
    for (int i = 0; i < 4; i++) af[i]  = *(const bf8*)&lA[(wm + i * 16 + l16) * 32 + quad * 8];
    #pragma unroll
    for (int j = 0; j < 4; j++) bfr[j] = *(const bf8*)&lB[(wn + j * 16 + l16) * 32 + quad * 8];
    #pragma unroll
    for (int i = 0; i < 4; i++)
      #pragma unroll
      for (int j = 0; j < 4; j++)
        acc[i][j] = __builtin_amdgcn_mfma_f32_16x16x32_bf16(af[i], bfr[j], acc[i][j], 0, 0, 0);
  }

  // epilogue: bias + act in registers, coalesced store via LDS f32 tile
  float bv[4];
  #pragma unroll
  for (int j = 0; j < 4; j++) bv[j] = b2f(bias[bn + wn + j * 16 + l16]);
  #pragma unroll
  for (int i = 0; i < 4; i++)
    #pragma unroll
    for (int j = 0; j < 4; j++)
      #pragma unroll
      for (int r = 0; r < 4; r++) {
        float v = acc[i][j][r] + bv[j];
        if (act) v = gelu_exact(v);
        acc[i][j][r] = v;
      }

  float* cf = (float*)smemc;
  const int whalf = wm >> 6;
  #pragma unroll
  for (int half = 0; half < 2; ++half) {
    __syncthreads();
    if (whalf == half) {
      #pragma unroll
      for (int i = 0; i < 4; i++)
        #pragma unroll
        for (int j = 0; j < 4; j++)
          #pragma unroll
          for (int r = 0; r < 4; r++)
            cf[(i * 16 + quad * 4 + r) * 128 + wn + j * 16 + l16] = acc[i][j][r];
    }
    __syncthreads();
    #pragma unroll
    for (int st = 0; st < 4; ++st) {
      const int e = st * 2048 + tid * 8;
      const int row = e >> 7;
      const size_t gbase = (size_t)(bm + half * 64 + row) * N + bn + (e & 127);
      u16x8 o;
      #pragma unroll
      for (int u = 0; u < 8; u++) o[u] = f2b(cf[e + u]);
      *(u16x8*)&Y[gbase] = o;
    }
  }
}

// W2 GEMM + residual + dtype-branched final store. BM=128 x BN=64 tile,
// grid 64x4 = 256 blocks (1 block/CU) -> 4-deep LDS ring pipeline.
__global__ __launch_bounds__(256) void gemm_w2out(
    const unsigned short* __restrict__ A,     // hid [8192,1024]
    const unsigned short* __restrict__ W,     // W2 [256,1024]
    const unsigned short* __restrict__ bias,
    const unsigned short* __restrict__ Res,   // h rows bf16
    void* __restrict__ OUT, const int* __restrict__ flagp, long out_row0)
{
  __shared__ __align__(16) unsigned short smem[4 * 6144];   // 48 KB ring
  const int tid = threadIdx.x, lane = tid & 63, wave = tid >> 6;
  const int bm = blockIdx.x * 128, bn = blockIdx.y * 64;
  const int wm = (wave >> 1) * 64, wn = (wave & 1) * 32;
  const int quad = lane >> 4, l16 = lane & 15;
  const int K = 1024, N = 256;
  const bool obf = (*flagp) != 0;

  f32x4 acc[4][2] = {};
  const int r0 = tid >> 2;
  const int co = (tid & 3) * 8;
  const unsigned short* pa0 = &A[(size_t)(bm + r0) * K + co];
  const unsigned short* pa1 = &A[(size_t)(bm + r0 + 64) * K + co];
  const unsigned short* pb0 = &W[(size_t)(bn + r0) * K + co];
  const int nt = K >> 5;   // 32

  auto stage = [&](int t, int sl) {
    const int k0 = t << 5;
    unsigned short* b_ = &smem[sl * 6144 + tid * 8];
    gl_lds16(pa0 + k0, b_);
    gl_lds16(pa1 + k0, b_ + 2048);
    gl_lds16(pb0 + k0, b_ + 4096);
  };

  stage(0, 0); stage(1, 1); stage(2, 2);
  int scur = 0, snew = 3;
  for (int t = 0; t < nt; ++t) {
    if (t + 3 < nt) {
      stage(t + 3, snew);
      asm volatile("s_waitcnt vmcnt(9)" ::: "memory");
    } else if (t + 2 < nt) {
      asm volatile("s_waitcnt vmcnt(6)" ::: "memory");
    } else if (t + 1 < nt) {
      asm volatile("s_waitcnt vmcnt(3)" ::: "memory");
    } else {
      asm volatile("s_waitcnt vmcnt(0)" ::: "memory");
    }
    __builtin_amdgcn_s_barrier();
    __builtin_amdgcn_sched_barrier(0);

    const unsigned short* sa = &smem[scur * 6144];
    const unsigned short* sb = sa + 4096;
    bf8 af[4], bfr[2];
    #pragma unroll
    for (int i = 0; i < 4; i++) af[i]  = *(const bf8*)&sa[(wm + i * 16 + l16) * 32 + quad * 8];
    #pragma unroll
    for (int j = 0; j < 2; j++) bfr[j] = *(const bf8*)&sb[(wn + j * 16 + l16) * 32 + quad * 8];
    #pragma unroll
    for (int i = 0; i < 4; i++)
      #pragma unroll
      for (int j = 0; j < 2; j++)
        acc[i][j] = __builtin_amdgcn_mfma_f32_16x16x32_bf16(af[i], bfr[j], acc[i][j], 0, 0, 0);

    __builtin_amdgcn_sched_barrier(0);
    __builtin_amdgcn_s_barrier();
    scur = scur + 1 < 4 ? scur + 1 : 0;
    snew = snew + 1 < 4 ? snew + 1 : 0;
  }

  // epilogue: bias in registers; f32 half-tile 64x64 via LDS; coalesced out.
  float bv[2];
  #pragma unroll
  for (int j = 0; j < 2; j++) bv[j] = b2f(bias[bn + wn + j * 16 + l16]);
  #pragma unroll
  for (int i = 0; i < 4; i++)
    #pragma unroll
    for (int j = 0; j < 2; j++)
      #pragma unroll
      for (int r = 0; r < 4; r++) acc[i][j][r] += bv[j];

  float* cf = (float*)smem;
  const int whalf = wm >> 6;
  #pragma unroll
  for (int half = 0; half < 2; ++half) {
    __builtin_amdgcn_s_barrier();
    if (whalf == half) {
      #pragma unroll
      for (int i = 0; i < 4; i++)
        #pragma unroll
        for (int j = 0; j < 2; j++)
          #pragma unroll
          for (int r = 0; r < 4; r++)
            cf[(i * 16 + quad * 4 + r) * 64 + wn + j * 16 + l16] = acc[i][j][r];
    }
    __builtin_amdgcn_s_barrier();
    #pragma unroll
    for (int st = 0; st < 2; ++st) {
      const int e = st * 2048 + tid * 8;
      const int row = e >> 6;
      const int grow = bm + half * 64 + row;
      const size_t rbase = (size_t)grow * N + bn + (e & 63);
      const size_t obase = (size_t)(out_row0 + grow) * N + bn + (e & 63);
      u16x8 rv = *(const u16x8*)&Res[rbase];
      float v[8];
      #pragma unroll
      for (int u = 0; u < 8; u++) v[u] = cf[e + u] + b2f(rv[u]);
      if (obf) {
        u16x8 o;
        #pragma unroll
        for (int u = 0; u < 8; u++) o[u] = f2b(v[u]);
        *(u16x8*)&((unsigned short*)OUT)[obase] = o;
      } else {
        f32x4 oa, ob;
        oa[0]=v[0]; oa[1]=v[1]; oa[2]=v[2]; oa[3]=v[3];
        ob[0]=v[4]; ob[1]=v[5]; ob[2]=v[6]; ob[3]=v[7];
        *(f32x4*)&((float*)OUT)[obase] = oa;
        *(f32x4*)&((float*)OUT)[obase + 4] = ob;
      }
    }
  }
}

// ---------------------------------------------------------------------------
// accumG: per 256-token block k: partial G[h,s,d] = sum_n E[n,h*32+s]*X[n,h*32+d]
// (+ z partial at [8192+tid]). Batch b owns blocks k = b*32 .. b*32+31.
// ---------------------------------------------------------------------------
__global__ __launch_bounds__(256) void accumG(
    const unsigned short* __restrict__ X,
    const unsigned short* __restrict__ E,
    float* __restrict__ Gp)                 // [256][8448]
{
  __shared__ float Xl[64 * 256];                         // 64 KB
  __shared__ __align__(16) unsigned short El[64 * 256];  // 32 KB
  const int tid = threadIdx.x;
  const int k = blockIdx.x;
  const int h = tid >> 5, s = tid & 31;

  float acc[32];
  #pragma unroll
  for (int d = 0; d < 32; d++) acc[d] = 0.f;
  float zacc = 0.f;

  for (int sub = 0; sub < 4; sub++) {
    const size_t r0s = (size_t)k * 256 + sub * 64;
    __syncthreads();
    #pragma unroll
    for (int i = 0; i < 8; i++) {
      const int flat = i * 2048 + tid * 8;
      u16x8 xv = *(const u16x8*)&X[r0s * 256 + flat];
      #pragma unroll
      for (int e = 0; e < 8; e++) Xl[flat + e] = b2f(xv[e]);
      *(u16x8*)&El[flat] = *(const u16x8*)&E[r0s * 256 + flat];
    }
    __syncthreads();

    for (int t = 0; t < 64; t++) {
      const float e = b2f(El[t * 256 + h * 32 + s]);
      zacc += e;
      const int xb = t * 256 + h * 32;
      #pragma unroll
      for (int dq = 0; dq < 8; dq++) {
        f32x4 xv = *(const f32x4*)&Xl[xb + dq * 4];
        acc[dq*4+0] += e * xv[0];
        acc[dq*4+1] += e * xv[1];
        acc[dq*4+2] += e * xv[2];
        acc[dq*4+3] += e * xv[3];
      }
    }
  }

  float* gp = &Gp[(size_t)k * 8448 + (size_t)tid * 32];
  #pragma unroll
  for (int dq = 0; dq < 8; dq++) {
    f32x4 o; o[0]=acc[dq*4]; o[1]=acc[dq*4+1]; o[2]=acc[dq*4+2]; o[3]=acc[dq*4+3];
    *(f32x4*)&gp[dq * 4] = o;
  }
  Gp[(size_t)k * 8448 + 8192 + tid] = zacc;
}

// Gfin[b][j] = sum_{i<32} Gp[b*32+i][j], b in 0..7.
__global__ __launch_bounds__(256) void reduceG(const float* __restrict__ Gp,
                                               float* __restrict__ Gfin) {
  const int o = blockIdx.x * 256 + threadIdx.x;
  if (o >= 67584) return;
  const int b = o / 8448;
  const int j = o - b * 8448;
  float s = 0.f;
  #pragma unroll 8
  for (int i = 0; i < 32; i++) s += Gp[(size_t)(b * 32 + i) * 8448 + j];
  Gfin[o] = s;
}

// kv_build (8 blocks): kv[b,h,s,d] = (sum_dd G*Wv[d,dd]) / z; block-diag KVB.
__global__ __launch_bounds__(256) void kv_build(
    const float* __restrict__ Gfin, const unsigned short* __restrict__ Wv,
    unsigned short* __restrict__ KVB)
{
  __shared__ float Gl[8192];
  __shared__ float zl[256];
  __shared__ float wvt[1024];
  const int tid = threadIdx.x;
  const int b = blockIdx.x;
  for (int i = tid; i < 8192; i += 256) Gl[i] = Gfin[(size_t)b * 8448 + i];
  zl[tid] = Gfin[(size_t)b * 8448 + 8192 + tid];
  for (int i = tid; i < 1024; i += 256) {
    const int dd = i >> 5, d = i & 31;
    wvt[i] = b2f(Wv[d * 32 + dd]);
  }
  __syncthreads();

  const int h = tid >> 5, d = tid & 31;
  unsigned short row[32];
  for (int s = 0; s < 32; s++) {
    float a = 0.f;
    #pragma unroll
    for (int dd = 0; dd < 32; dd++) a += Gl[h * 1024 + s * 32 + dd] * wvt[dd * 32 + d];
    row[s] = f2b(a / zl[h * 32 + s]);
  }
  unsigned short* out = &KVB[(size_t)b * 65536 + (size_t)(h * 32 + d) * 256 + h * 32];
  #pragma unroll
  for (int e = 0; e < 4; e++) *(u16x8*)&out[e * 8] = *(u16x8*)&row[e * 8];
}

__global__ __launch_bounds__(256) void copy_h0(const unsigned short* __restrict__ src,
                                               unsigned short* __restrict__ dst) {
  size_t i = ((size_t)blockIdx.x * 256 + threadIdx.x) * 8;
  *(u16x8*)&dst[i] = *(const u16x8*)&src[i];
}

// ---------------------------------------------------------------------------
extern "C" void kernel_launch(void* const* d_in, const int* in_sizes, int n_in,
                              void* d_out, int out_size, void* d_ws, size_t ws_size,
                              hipStream_t stream)
{
  const void* fx   = d_in[0];
  const void* ln1w = d_in[1];
  const void* ln1b = d_in[2];
  const void* Wx   = d_in[3];
  const void* bx   = d_in[4];
  const void* Wq   = d_in[5];
  const void* Wk   = d_in[6];
  const void* Wv   = d_in[7];
  const void* Wo   = d_in[8];
  const void* bo   = d_in[9];
  const void* ln2w = d_in[10];
  const void* ln2b = d_in[11];
  const void* W1   = d_in[12];
  const void* b1   = d_in[13];
  const void* W2   = d_in[14];
  const void* b2   = d_in[15];

  // ws layout (~24.7 MB)
  unsigned short* ws    = (unsigned short*)d_ws;
  unsigned short* hid   = ws;                      // 8,388,608 u16 (16 MB)
  float* Gp             = (float*)ws;              // overlay: 256*8448 f32
  unsigned short* wtab  = ws + 8388608;            // 661,248 u16
  unsigned short* h0res = wtab + 661248;           // 2,097,152 u16 (4 MB)
  float* Gfin           = (float*)h0res;           // overlay: 67,584 f32
  unsigned short* Wqbig = h0res + 2097152;         // 65,536
  unsigned short* Wkbig = Wqbig + 65536;           // 65,536
  unsigned short* KVB   = Wkbig + 65536;           // 524,288
  unsigned short* zbias = KVB + 524288;            // 256
  float* fpw = (float*)(zbias + 256);
  float* mu1 = fpw;
  float* rs1 = fpw + 65536;
  float* mu2 = fpw + 131072;
  float* rs2 = fpw + 196608;
  int* flagp = (int*)(fpw + 262144);

  const int OFF_LN1W=0, OFF_LN1B=256, OFF_WX=512, OFF_BX=66048,
            OFF_WQ=66304, OFF_WK=67328, OFF_WV=68352,
            OFF_WO=69376, OFF_BO=134912, OFF_LN2W=135168, OFF_LN2B=135424,
            OFF_W1=135680, OFF_B1=397824, OFF_W2=398848, OFF_B2=660992;

  unsigned short* xm  = (unsigned short*)d_out;    // lower: xmid->qkv2d (dead after Wo)
  unsigned short* xup = xm + 16777216;             // upper: E2d->QL->Qs->h

  // 0. dtype sniff + weight table
  sniff_kernel<<<1, 64, 0, stream>>>((const unsigned*)fx, flagp);
  CvtDesc cd;
  const void* srcs[15] = {ln1w, ln1b, Wx, bx, Wq, Wk, Wv, Wo, bo, ln2w, ln2b, W1, b1, W2, b2};
  const int offs[15]   = {OFF_LN1W, OFF_LN1B, OFF_WX, OFF_BX, OFF_WQ, OFF_WK, OFF_WV,
                          OFF_WO, OFF_BO, OFF_LN2W, OFF_LN2B, OFF_W1, OFF_B1, OFF_W2, OFF_B2};
  const int ns[15]     = {256, 256, 65536, 256, 1024, 1024, 1024, 65536, 256, 256, 256,
                          262144, 1024, 262144, 256};
  for (int i = 0; i < 15; i++) { cd.src[i] = srcs[i]; cd.off[i] = offs[i]; cd.n[i] = ns[i]; }
  cvt_tab<<<dim3(1024, 15), 256, 0, stream>>>(cd, wtab, flagp);
  build_big<<<256, 256, 0, stream>>>(wtab + OFF_WQ, wtab + OFF_WK, Wqbig, Wkbig);
  zero_u16<<<257, 256, 0, stream>>>(KVB, 524544);

  // 1. LN1 stats; xmid = LN1(fx) @ Wx^T + bx -> xm
  ln_stats<<<16384, 256, 0, stream>>>(fx, flagp, 1, mu1, rs1);
  gemm_bt_ln<<<dim3(512, 2), 256, 0, stream>>>(fx, flagp, 1, mu1, rs1,
      wtab + OFF_LN1W, wtab + OFF_LN1B, wtab + OFF_WX, wtab + OFF_BX,
      xm, 256, 256, 0);

  // 2. E2d = exp(xmid @ Wkbig^T) -> xup
  gemm_bt<<<dim3(512, 2), 256, 0, stream>>>(xm, Wkbig, zbias, nullptr, flagp,
                                            xup, 256, 256, 2, 0, 0);

  // 3. G partials + reduce; kv -> KVB block-diag
  accumG<<<256, 256, 0, stream>>>(xm, xup, Gp);
  reduceG<<<264, 256, 0, stream>>>(Gp, Gfin);
  kv_build<<<8, 256, 0, stream>>>(Gfin, wtab + OFF_WV, KVB);

  // 4. Qs = segsoftmax(xmid @ Wqbig^T) -> xup (E2d dead), fused in epilogue
  gemm_bt<<<dim3(512, 2), 256, 0, stream>>>(xm, Wqbig, zbias, nullptr, flagp,
                                            xup, 256, 256, 3, 0, 0);

  // 5. qkv2d = Qs @ KVB[b]^T -> xm (xmid dead), z-batched over b
  gemm_bt<<<dim3(64, 2, 8), 256, 0, stream>>>(xup, KVB, zbias, nullptr, flagp,
                                              xm, 256, 256, 0, 8192, 65536);

  // 6. h = qkv2d @ Wo^T + bo + fx -> xup (Qs dead; NOT in-place -> full grid)
  gemm_bt<<<dim3(512, 2), 256, 0, stream>>>(xm, wtab + OFF_WO, wtab + OFF_BO, fx, flagp,
                                            xup, 256, 256, 0, 0, 0);

  // 7. LN2 stats on h; protect chunk-7 residual (out writes reach h7 last)
  ln_stats<<<16384, 256, 0, stream>>>(xup, flagp, 0, mu2, rs2);
  copy_h0<<<1024, 256, 0, stream>>>(xup + (size_t)7 * 2097152, h0res);

  // 8. MLP, 8 chunks of 8192 rows, ASCENDING. Out writes [0,8c) MB never touch
  //    h chunk c at [32+4c,36+4c) MB for c<8; only chunk 7's own W2out would
  //    race with its residual -> uses h0res copy. Gp dead -> hid usable.
  for (int c = 0; c < 8; c++) {
    unsigned short* hrows = xup + (size_t)c * 2097152;
    gemm_bt_ln<<<dim3(64, 8), 256, 0, stream>>>(hrows, flagp, 0,
        mu2 + c * 8192, rs2 + c * 8192, wtab + OFF_LN2W, wtab + OFF_LN2B,
        wtab + OFF_W1, wtab + OFF_B1, hid, 1024, 256, 1);
    gemm_w2out<<<dim3(64, 4), 256, 0, stream>>>(hid, wtab + OFF_W2, wtab + OFF_B2,
        (c == 7 ? h0res : hrows), d_out, flagp, (long)c * 8192);
  }
}

// Round 2
// 507.254 us; speedup vs baseline: 1.4819x; 1.2734x over previous
//
#include <hip/hip_runtime.h>
#include <math.h>

// ---------------------------------------------------------------------------
// LinearNO block, MI355X/gfx950. Inputs fp32 (sniffed; bf16 fallback).
// Interior bf16 MFMA. B=8 N=8192 C=256 H=8 D=32 S=32.
//
// R9 changes vs R8 (646 us):
//  * MLP fully fused: fused_mlp computes GELU(LN2(h)@W1^T+b1)@W2^T+b2+h per
//    64-row block, hid tile lives in LDS (t, 64x32 per chunk) -- kills the
//    256 MB hid HBM round-trip and the 16-dispatch chunk loop.
//    W1/W2 chunks staged via global_load_lds with XOR-swizzled SOURCE addrs
//    (linear LDS dest) so all ds_read_b128 are bank-balanced.
//  * write-order safety without timing assumptions: h upper half copied to
//    ws (hid area dead); launch 1 (rows<32768) writes only dead xm bytes,
//    launch 2 reads only the copy.
//  * gemm_w2out deleted.
// ---------------------------------------------------------------------------

typedef __attribute__((ext_vector_type(8))) short bf8;
typedef __attribute__((ext_vector_type(4))) float f32x4;
typedef __attribute__((ext_vector_type(4))) unsigned short u16x4;
typedef __attribute__((ext_vector_type(8))) unsigned short u16x8;

__device__ __forceinline__ float b2f(unsigned short x) {
  union { unsigned u; float f; } t; t.u = ((unsigned)x) << 16; return t.f;
}
__device__ __forceinline__ unsigned short f2b(float f) {
  union { float f; unsigned u; } t; t.f = f;
  unsigned r = t.u + 0x7fffu + ((t.u >> 16) & 1u);
  return (unsigned short)(r >> 16);
}
__device__ __forceinline__ float gelu_exact(float x) {
  return 0.5f * x * (1.0f + erff(x * 0.7071067811865475f));
}

// async global->LDS, 16 B per lane. LDS dest must be base + lane*16.
typedef __attribute__((address_space(1))) const void gas_void;
typedef __attribute__((address_space(3))) void las_void;
__device__ __forceinline__ void gl_lds16(const void* g, void* l) {
  __builtin_amdgcn_global_load_lds((gas_void*)g, (las_void*)l, 16, 0, 0);
}

// --------------------------- dtype sniffer ---------------------------------
__global__ void sniff_kernel(const unsigned* __restrict__ fx, int* __restrict__ flag) {
  if (threadIdx.x == 0) {
    int cnt = 0;
    for (int i = 0; i < 64; i++) {
      unsigned e = (fx[i] >> 7) & 0xFFu;
      cnt += (e >= 117u && e <= 130u) ? 1 : 0;
    }
    *flag = (cnt >= 32) ? 1 : 0;   // 1 = bf16 inputs, 0 = fp32
  }
}

// --------------------------- weight table ----------------------------------
struct CvtDesc { const void* src[15]; int off[15]; int n[15]; };

__global__ __launch_bounds__(256) void cvt_tab(CvtDesc d, unsigned short* __restrict__ wtab,
                                               const int* __restrict__ flagp) {
  const int seg = blockIdx.y;
  const int i = blockIdx.x * 256 + threadIdx.x;
  if (i >= d.n[seg]) return;
  unsigned short o;
  if (*flagp) o = ((const unsigned short*)d.src[seg])[i];
  else        o = f2b(((const float*)d.src[seg])[i]);
  wtab[d.off[seg] + i] = o;
}

// Block-diagonal Wq_big / Wk_big [256,256]: big[h*32+s][h*32+d]=W[s][d].
__global__ __launch_bounds__(256) void build_big(
    const unsigned short* __restrict__ wq, const unsigned short* __restrict__ wk,
    unsigned short* __restrict__ Wqbig, unsigned short* __restrict__ Wkbig)
{
  const int idx = blockIdx.x * 256 + threadIdx.x;
  const int row = idx >> 8, col = idx & 255;
  const bool same = (row >> 5) == (col >> 5);
  const int wi = (row & 31) * 32 + (col & 31);
  Wqbig[idx] = same ? wq[wi] : (unsigned short)0;
  Wkbig[idx] = same ? wk[wi] : (unsigned short)0;
}

__global__ __launch_bounds__(256) void zero_u16(unsigned short* __restrict__ p, int n) {
  int i8 = (blockIdx.x * 256 + threadIdx.x) * 8;
  if (i8 < n) { u16x8 z = {}; *(u16x8*)&p[i8] = z; }
}

// --------------------------- LN stats --------------------------------------
__global__ __launch_bounds__(256) void ln_stats(
    const void* __restrict__ X, const int* __restrict__ flagp, int amode,
    float* __restrict__ MU, float* __restrict__ RS)
{
  const int lane = threadIdx.x & 63;
  const int wave = threadIdx.x >> 6;
  const size_t row = (size_t)blockIdx.x * 4 + wave;
  const size_t base = row * 256 + lane * 4;
  const bool abf = amode ? ((*flagp) != 0) : true;
  float x0, x1, x2, x3;
  if (abf) {
    u16x4 uv = *(const u16x4*)&((const unsigned short*)X)[base];
    x0 = b2f(uv[0]); x1 = b2f(uv[1]); x2 = b2f(uv[2]); x3 = b2f(uv[3]);
  } else {
    f32x4 t = *(const f32x4*)&((const float*)X)[base];
    x0 = t[0]; x1 = t[1]; x2 = t[2]; x3 = t[3];
  }
  float s = x0 + x1 + x2 + x3;
  float q = x0*x0 + x1*x1 + x2*x2 + x3*x3;
  #pragma unroll
  for (int m = 1; m < 64; m <<= 1) { s += __shfl_xor(s, m, 64); q += __shfl_xor(q, m, 64); }
  float mean = s * (1.0f / 256.0f);
  float var  = q * (1.0f / 256.0f) - mean * mean;
  if (lane == 0) { MU[row] = mean; RS[row] = rsqrtf(var + 1e-5f); }
}

// --------------------------- generic MFMA GEMM (pipelined) ------------------
// Y[.,N] = A @ W^T + bias (+Res dtype-branched) ; act: 0 none, 2 exp,
// 3 segment-softmax (32-col segments, fused jax.nn.softmax over slices).
// 128x128 tile; 3-slot LDS ring, stage t+2 while computing t, counted vmcnt.
// z-batch: rows += z*mz, W += z*wz.
__global__ __launch_bounds__(256) void gemm_bt(
    const unsigned short* __restrict__ A,
    const unsigned short* __restrict__ W,
    const unsigned short* __restrict__ bias,
    const void* __restrict__ Res, const int* __restrict__ flagp,
    unsigned short* __restrict__ Y,
    int N, int K, int act, int mz, long wz)
{
  __shared__ __align__(16) unsigned short smem[3 * 8192];   // 48 KB ring
  const int tid = threadIdx.x, lane = tid & 63, wave = tid >> 6;
  const size_t zrow = (size_t)blockIdx.z * mz;
  const int bm = blockIdx.x * 128, bn = blockIdx.y * 128;
  const int wm = (wave >> 1) * 64, wn = (wave & 1) * 64;
  const int quad = lane >> 4, l16 = lane & 15;
  const unsigned short* Wz = W + (size_t)blockIdx.z * wz;

  f32x4 acc[4][4] = {};
  const int r0 = tid >> 2;
  const int co = (tid & 3) * 8;
  const unsigned short* pa0 = &A[(zrow + bm + r0) * K + co];
  const unsigned short* pa1 = &A[(zrow + bm + r0 + 64) * K + co];
  const unsigned short* pb0 = &Wz[(size_t)(bn + r0) * K + co];
  const unsigned short* pb1 = &Wz[(size_t)(bn + r0 + 64) * K + co];
  const int nt = K >> 5;

  auto stage = [&](int t, int sl) {
    const int k0 = t << 5;
    unsigned short* b_ = &smem[sl * 8192 + tid * 8];
    gl_lds16(pa0 + k0, b_);
    gl_lds16(pa1 + k0, b_ + 2048);
    gl_lds16(pb0 + k0, b_ + 4096);
    gl_lds16(pb1 + k0, b_ + 6144);
  };

  stage(0, 0);
  if (nt > 1) stage(1, 1);
  int scur = 0, snew = 2;
  for (int t = 0; t < nt; ++t) {
    if (t + 2 < nt) {
      stage(t + 2, snew);
      asm volatile("s_waitcnt vmcnt(8)" ::: "memory");   // tile t landed (mine)
    } else if (t + 1 < nt) {
      asm volatile("s_waitcnt vmcnt(4)" ::: "memory");
    } else {
      asm volatile("s_waitcnt vmcnt(0)" ::: "memory");
    }
    __builtin_amdgcn_s_barrier();                        // tile t landed (all)
    __builtin_amdgcn_sched_barrier(0);

    const unsigned short* sa = &smem[scur * 8192];
    const unsigned short* sb = sa + 4096;
    bf8 af[4], bfr[4];
    #pragma unroll
    for (int i = 0; i < 4; i++) af[i]  = *(const bf8*)&sa[(wm + i * 16 + l16) * 32 + quad * 8];
    #pragma unroll
    for (int j = 0; j < 4; j++) bfr[j] = *(const bf8*)&sb[(wn + j * 16 + l16) * 32 + quad * 8];
    #pragma unroll
    for (int i = 0; i < 4; i++)
      #pragma unroll
      for (int j = 0; j < 4; j++)
        acc[i][j] = __builtin_amdgcn_mfma_f32_16x16x32_bf16(af[i], bfr[j], acc[i][j], 0, 0, 0);

    __builtin_amdgcn_sched_barrier(0);
    __builtin_amdgcn_s_barrier();                        // all waves done reading slot
    scur = scur + 1 < 3 ? scur + 1 : 0;
    snew = snew + 1 < 3 ? snew + 1 : 0;
  }

  // ---- epilogue: bias/act in registers, f32 tile via LDS, coalesced stores
  const bool rbf = Res ? ((*flagp) != 0) : true;
  float bv[4];
  #pragma unroll
  for (int j = 0; j < 4; j++) bv[j] = b2f(bias[bn + wn + j * 16 + l16]);
  #pragma unroll
  for (int i = 0; i < 4; i++)
    #pragma unroll
    for (int j = 0; j < 4; j++)
      #pragma unroll
      for (int r = 0; r < 4; r++) {
        float v = acc[i][j][r] + bv[j];
        if (act == 2) v = __expf(v);
        acc[i][j][r] = v;
      }
  if (act == 3) {
    #pragma unroll
    for (int i = 0; i < 4; i++)
      #pragma unroll
      for (int g = 0; g < 2; g++)
        #pragma unroll
        for (int r = 0; r < 4; r++) {
          float a0 = acc[i][2*g][r], a1 = acc[i][2*g+1][r];
          float m = fmaxf(a0, a1);
          #pragma unroll
          for (int msk = 1; msk < 16; msk <<= 1) m = fmaxf(m, __shfl_xor(m, msk, 64));
          float e0 = __expf(a0 - m), e1 = __expf(a1 - m);
          float s = e0 + e1;
          #pragma unroll
          for (int msk = 1; msk < 16; msk <<= 1) s += __shfl_xor(s, msk, 64);
          const float rz = 1.0f / s;
          acc[i][2*g][r] = e0 * rz; acc[i][2*g+1][r] = e1 * rz;
        }
  }

  float* cf = (float*)smem;              // 64x128 f32 half-tile (32 KB)
  const int whalf = wm >> 6;
  #pragma unroll
  for (int half = 0; half < 2; ++half) {
    __builtin_amdgcn_s_barrier();
    if (whalf == half) {
      #pragma unroll
      for (int i = 0; i < 4; i++)
        #pragma unroll
        for (int j = 0; j < 4; j++)
          #pragma unroll
          for (int r = 0; r < 4; r++)
            cf[(i * 16 + quad * 4 + r) * 128 + wn + j * 16 + l16] = acc[i][j][r];
    }
    __builtin_amdgcn_s_barrier();
    #pragma unroll
    for (int st = 0; st < 4; ++st) {
      const int e = st * 2048 + tid * 8;
      const int row = e >> 7;
      const size_t gbase = (zrow + bm + half * 64 + row) * (size_t)N + bn + (e & 127);
      float v[8];
      #pragma unroll
      for (int u = 0; u < 8; u++) v[u] = cf[e + u];
      if (Res) {
        if (rbf) {
          u16x8 rv = *(const u16x8*)&((const unsigned short*)Res)[gbase];
          #pragma unroll
          for (int u = 0; u < 8; u++) v[u] += b2f(rv[u]);
        } else {
          f32x4 ra = *(const f32x4*)&((const float*)Res)[gbase];
          f32x4 rb = *(const f32x4*)&((const float*)Res)[gbase + 4];
          v[0] += ra[0]; v[1] += ra[1]; v[2] += ra[2]; v[3] += ra[3];
          v[4] += rb[0]; v[5] += rb[1]; v[6] += rb[2]; v[7] += rb[3];
        }
      }
      u16x8 o;
      #pragma unroll
      for (int u = 0; u < 8; u++) o[u] = f2b(v[u]);
      *(u16x8*)&Y[gbase] = o;
    }
  }
}

// GEMM with LN applied to A during staging (amode: 1=flag dtype, 0=bf16);
// B side uses DMA staging. act=1 -> GELU. Coalesced LDS epilogue.
__global__ __launch_bounds__(256) void gemm_bt_ln(
    const void* __restrict__ A, const int* __restrict__ flagp, int amode,
    const float* __restrict__ MU, const float* __restrict__ RS,
    const unsigned short* __restrict__ lw, const unsigned short* __restrict__ lb,
    const unsigned short* __restrict__ W, const unsigned short* __restrict__ bias,
    unsigned short* __restrict__ Y, int N, int K, int act)
{
  __shared__ __align__(16) unsigned char smemc[32768];       // lA+lB, cf overlay
  unsigned short* lA = (unsigned short*)smemc;
  unsigned short* lB = lA + 4096;
  const int tid = threadIdx.x, lane = tid & 63, wave = tid >> 6;
  const int bm = blockIdx.x * 128, bn = blockIdx.y * 128;
  const int wm = (wave >> 1) * 64, wn = (wave & 1) * 64;
  const int quad = lane >> 4, l16 = lane & 15;
  const bool abf = amode ? ((*flagp) != 0) : true;
  const unsigned short* Ab = (const unsigned short*)A;
  const float* Af = (const float*)A;

  f32x4 acc[4][4] = {};
  const int r0 = tid >> 2;
  const int co = (tid & 3) * 8;
  const unsigned short* pb0 = &W[(size_t)(bn + r0) * K + co];
  const unsigned short* pb1 = &W[(size_t)(bn + r0 + 64) * K + co];

  for (int k0 = 0; k0 < K; k0 += 32) {
    u16x8 wv8 = *(const u16x8*)&lw[k0 + co];
    u16x8 bv8 = *(const u16x8*)&lb[k0 + co];
    __syncthreads();
    gl_lds16(pb0 + k0, &lB[tid * 8]);
    gl_lds16(pb1 + k0, &lB[2048 + tid * 8]);
    #pragma unroll
    for (int half = 0; half < 2; half++) {
      const int ar = bm + r0 + half * 64;
      const float m_ = MU[ar], r_ = RS[ar];
      float xv[8];
      if (abf) {
        u16x8 t = *(const u16x8*)&Ab[(size_t)ar * K + k0 + co];
        #pragma unroll
        for (int e = 0; e < 8; e++) xv[e] = b2f(t[e]);
      } else {
        f32x4 t0 = *(const f32x4*)&Af[(size_t)ar * K + k0 + co];
        f32x4 t1 = *(const f32x4*)&Af[(size_t)ar * K + k0 + co + 4];
        xv[0]=t0[0]; xv[1]=t0[1]; xv[2]=t0[2]; xv[3]=t0[3];
        xv[4]=t1[0]; xv[5]=t1[1]; xv[6]=t1[2]; xv[7]=t1[3];
      }
      u16x8 o;
      #pragma unroll
      for (int e = 0; e < 8; e++)
        o[e] = f2b((xv[e] - m_) * r_ * b2f(wv8[e]) + b2f(bv8[e]));
      *(u16x8*)&lA[half * 2048 + tid * 8] = o;
    }
    __syncthreads();

    bf8 af[4], bfr[4];
    #pragma unroll
    for (int i = 0; i < 4; i++) af[i]  = *(const bf8*)&lA[(wm + i * 16 + l16) * 32 + quad * 8];
    #pragma unroll
    for (int j = 0; j < 4; j++) bfr[j] = *(const bf8*)&lB[(wn + j * 16 + l16) * 32 + quad * 8];
    #pragma unroll
    for (int i = 0; i < 4; i++)
      #pragma unroll
      for (int j = 0; j < 4; j++)
        acc[i][j] = __builtin_amdgcn_mfma_f32_16x16x32_bf16(af[i], bfr[j], acc[i][j], 0, 0, 0);
  }

  // epilogue: bias + act in registers, coalesced store via LDS f32 tile
  float bv[4];
  #pragma unroll
  for (int j = 0; j < 4; j++) bv[j] = b2f(bias[bn + wn + j * 16 + l16]);
  #pragma unroll
  for (int i = 0; i < 4; i++)
    #pragma unroll
    for (int j = 0; j < 4; j++)
      #pragma unroll
      for (int r = 0; r < 4; r++) {
        float v = acc[i][j][r] + bv[j];
        if (act) v = gelu_exact(v);
        acc[i][j][r] = v;
      }

  float* cf = (float*)smemc;
  const int whalf = wm >> 6;
  #pragma unroll
  for (int half = 0; half < 2; ++half) {
    __syncthreads();
    if (whalf == half) {
      #pragma unroll
      for (int i = 0; i < 4; i++)
        #pragma unroll
        for (int j = 0; j < 4; j++)
          #pragma unroll
          for (int r = 0; r < 4; r++)
            cf[(i * 16 + quad * 4 + r) * 128 + wn + j * 16 + l16] = acc[i][j][r];
    }
    __syncthreads();
    #pragma unroll
    for (int st = 0; st < 4; ++st) {
      const int e = st * 2048 + tid * 8;
      const int row = e >> 7;
      const size_t gbase = (size_t)(bm + half * 64 + row) * N + bn + (e & 127);
      u16x8 o;
      #pragma unroll
      for (int u = 0; u < 8; u++) o[u] = f2b(cf[e + u]);
      *(u16x8*)&Y[gbase] = o;
    }
  }
}

// ---------------------------------------------------------------------------
// fused_mlp: per 64-row block, y = GELU(LN2(h)@W1^T+b1)@W2^T + b2 + h.
// lnA [64][264] staged once (LN amortized); 32 chunks of 32 hid:
//   GEMM1: t[64x32] = lnA @ W1c^T (+b1, GELU) -> LDS (stride 80 B)
//   GEMM2: acc[64x256] += t @ W2c^T  (register accumulator)
// W1c/W2c via global_load_lds, XOR-swizzled source (linear dest), so
// ds_read_b128 bank-balanced. Counted vmcnt overlaps staging with compute.
// ---------------------------------------------------------------------------
__global__ __launch_bounds__(256) void fused_mlp(
    const unsigned short* __restrict__ Hsrc,
    const float* __restrict__ MU, const float* __restrict__ RS,
    const unsigned short* __restrict__ lw, const unsigned short* __restrict__ lb,
    const unsigned short* __restrict__ W1, const unsigned short* __restrict__ bs1,
    const unsigned short* __restrict__ W2, const unsigned short* __restrict__ bs2,
    void* __restrict__ OUT, const int* __restrict__ flagp, long row0)
{
  // LDS: lnA 64*528=33792 | W1c 16384 @33792 | W2c 16384 @50176 | t 64*80 @66560
  __shared__ __align__(16) unsigned char smem[71680];
  const int tid = threadIdx.x, lane = tid & 63, wave = tid >> 6;
  const int quad = lane >> 4, l16 = lane & 15;
  const int brow = blockIdx.x * 64;

  // ---- stage lnA (pad to 264 elems/row for bank balance)
  const unsigned short* hrow = Hsrc + (size_t)brow * 256;
  #pragma unroll
  for (int i = 0; i < 8; i++) {
    const int flat = i * 2048 + tid * 8;
    const int row = flat >> 8, col = flat & 255;
    u16x8 hv = *(const u16x8*)&hrow[flat];
    const float m_ = MU[brow + row], r_ = RS[brow + row];
    u16x8 wv = *(const u16x8*)&lw[col];
    u16x8 bv = *(const u16x8*)&lb[col];
    u16x8 o;
    #pragma unroll
    for (int e = 0; e < 8; e++)
      o[e] = f2b((b2f(hv[e]) - m_) * r_ * b2f(wv[e]) + b2f(bv[e]));
    *(u16x8*)(smem + row * 528 + col * 2) = o;
  }

  auto stageW1 = [&](int c) {
    const unsigned short* src = W1 + (size_t)c * 8192;   // 32 rows x 256
    #pragma unroll
    for (int s = 0; s < 4; s++) {
      const int unit = s * 256 + tid;
      const int row = unit >> 5, u = unit & 31;
      gl_lds16(src + row * 256 + (u ^ (row & 7)) * 8, smem + 33792 + unit * 16);
    }
  };
  auto stageW2 = [&](int c) {
    const unsigned short* src = W2 + c * 32;             // 256 rows x 32 (of 1024)
    #pragma unroll
    for (int s = 0; s < 4; s++) {
      const int unit = s * 256 + tid;
      const int row = unit >> 2, u = unit & 3;
      gl_lds16(src + (size_t)row * 1024 + (u ^ ((row ^ (row >> 2)) & 3)) * 8,
               smem + 50176 + unit * 16);
    }
  };

  f32x4 acc[4][4] = {};
  stageW1(0);
  stageW2(0);
  __syncthreads();     // drains vmcnt+lgkm: W1c(0),W2c(0),lnA all ready

  for (int c = 0; c < 32; ++c) {
    // ---- GEMM1: wave computes t rows [wave*16, wave*16+16) x 32 hid cols
    f32x4 at0 = {}, at1 = {};
    const int arow = wave * 16 + l16;
    #pragma unroll
    for (int ks = 0; ks < 8; ks++) {
      bf8 af = *(const bf8*)(smem + arow * 528 + ks * 64 + quad * 16);
      const int u0 = ks * 4 + quad;
      bf8 bw0 = *(const bf8*)(smem + 33792 + l16 * 512 + ((u0 ^ (l16 & 7)) * 16));
      bf8 bw1 = *(const bf8*)(smem + 33792 + (16 + l16) * 512 + ((u0 ^ (l16 & 7)) * 16));
      at0 = __builtin_amdgcn_mfma_f32_16x16x32_bf16(af, bw0, at0, 0, 0, 0);
      at1 = __builtin_amdgcn_mfma_f32_16x16x32_bf16(af, bw1, at1, 0, 0, 0);
    }
    // bias + exact GELU + write t (bf16, stride 80 B)
    {
      const float bb0 = b2f(bs1[c * 32 + l16]);
      const float bb1 = b2f(bs1[c * 32 + 16 + l16]);
      #pragma unroll
      for (int r = 0; r < 4; r++) {
        const int trow = wave * 16 + quad * 4 + r;
        unsigned short* tp = (unsigned short*)(smem + 66560 + trow * 80);
        tp[l16]      = f2b(gelu_exact(at0[r] + bb0));
        tp[16 + l16] = f2b(gelu_exact(at1[r] + bb1));
      }
    }
    __builtin_amdgcn_sched_barrier(0);
    asm volatile("s_waitcnt vmcnt(0) lgkmcnt(0)" ::: "memory");  // W2c(c) landed; t visible
    __builtin_amdgcn_s_barrier();
    __builtin_amdgcn_sched_barrier(0);

    if (c + 1 < 32) stageW1(c + 1);      // W1c buffer free; flies over GEMM2

    // ---- GEMM2: wave cols [wave*64, wave*64+64), acc += t @ W2c^T
    bf8 a2[4], bW[4];
    #pragma unroll
    for (int i = 0; i < 4; i++)
      a2[i] = *(const bf8*)(smem + 66560 + (i * 16 + l16) * 80 + quad * 16);
    #pragma unroll
    for (int j = 0; j < 4; j++) {
      const int crow = wave * 64 + j * 16 + l16;
      bW[j] = *(const bf8*)(smem + 50176 + crow * 64 +
                            ((quad ^ ((crow ^ (crow >> 2)) & 3)) * 16));
    }
    #pragma unroll
    for (int i = 0; i < 4; i++)
      #pragma unroll
      for (int j = 0; j < 4; j++)
        acc[i][j] = __builtin_amdgcn_mfma_f32_16x16x32_bf16(a2[i], bW[j], acc[i][j], 0, 0, 0);

    __builtin_amdgcn_sched_barrier(0);
    __builtin_amdgcn_s_barrier();        // t + W2c free
    if (c + 1 < 32) stageW2(c + 1);
    asm volatile("s_waitcnt vmcnt(4)" ::: "memory");   // W1c(c+1) landed
    __builtin_amdgcn_s_barrier();
    __builtin_amdgcn_sched_barrier(0);
  }

  // ---- epilogue: acc -> cf [64][256] f32, then coalesced residual+store
  float* cf = (float*)smem;
  #pragma unroll
  for (int i = 0; i < 4; i++)
    #pragma unroll
    for (int j = 0; j < 4; j++)
      #pragma unroll
      for (int r = 0; r < 4; r++)
        cf[(i * 16 + quad * 4 + r) * 256 + wave * 64 + j * 16 + l16] = acc[i][j][r];
  __syncthreads();
  const bool obf = (*flagp) != 0;
  #pragma unroll
  for (int s = 0; s < 8; s++) {
    const int e = s * 2048 + tid * 8;
    const int row = e >> 8, col = e & 255;
    u16x8 rv = *(const u16x8*)&hrow[e];
    u16x8 b2v = *(const u16x8*)&bs2[col];
    float v[8];
    #pragma unroll
    for (int u = 0; u < 8; u++) v[u] = cf[e + u] + b2f(rv[u]) + b2f(b2v[u]);
    const size_t ob = (size_t)(row0 + brow + row) * 256 + col;
    if (obf) {
      u16x8 o;
      #pragma unroll
      for (int u = 0; u < 8; u++) o[u] = f2b(v[u]);
      *(u16x8*)&((unsigned short*)OUT)[ob] = o;
    } else {
      f32x4 oa, obv;
      oa[0]=v[0]; oa[1]=v[1]; oa[2]=v[2]; oa[3]=v[3];
      obv[0]=v[4]; obv[1]=v[5]; obv[2]=v[6]; obv[3]=v[7];
      *(f32x4*)&((float*)OUT)[ob] = oa;
      *(f32x4*)&((float*)OUT)[ob + 4] = obv;
    }
  }
}

// ---------------------------------------------------------------------------
// accumG: per 256-token block k: partial G[h,s,d] = sum_n E[n,h*32+s]*X[n,h*32+d]
// (+ z partial at [8192+tid]). Batch b owns blocks k = b*32 .. b*32+31.
// ---------------------------------------------------------------------------
__global__ __launch_bounds__(256) void accumG(
    const unsigned short* __restrict__ X,
    const unsigned short* __restrict__ E,
    float* __restrict__ Gp)                 // [256][8448]
{
  __shared__ float Xl[64 * 256];                         // 64 KB
  __shared__ __align__(16) unsigned short El[64 * 256];  // 32 KB
  const int tid = threadIdx.x;
  const int k = blockIdx.x;
  const int h = tid >> 5, s = tid & 31;

  float acc[32];
  #pragma unroll
  for (int d = 0; d < 32; d++) acc[d] = 0.f;
  float zacc = 0.f;

  for (int sub = 0; sub < 4; sub++) {
    const size_t r0s = (size_t)k * 256 + sub * 64;
    __syncthreads();
    #pragma unroll
    for (int i = 0; i < 8; i++) {
      const int flat = i * 2048 + tid * 8;
      u16x8 xv = *(const u16x8*)&X[r0s * 256 + flat];
      #pragma unroll
      for (int e = 0; e < 8; e++) Xl[flat + e] = b2f(xv[e]);
      *(u16x8*)&El[flat] = *(const u16x8*)&E[r0s * 256 + flat];
    }
    __syncthreads();

    for (int t = 0; t < 64; t++) {
      const float e = b2f(El[t * 256 + h * 32 + s]);
      zacc += e;
      const int xb = t * 256 + h * 32;
      #pragma unroll
      for (int dq = 0; dq < 8; dq++) {
        f32x4 xv = *(const f32x4*)&Xl[xb + dq * 4];
        acc[dq*4+0] += e * xv[0];
        acc[dq*4+1] += e * xv[1];
        acc[dq*4+2] += e * xv[2];
        acc[dq*4+3] += e * xv[3];
      }
    }
  }

  float* gp = &Gp[(size_t)k * 8448 + (size_t)tid * 32];
  #pragma unroll
  for (int dq = 0; dq < 8; dq++) {
    f32x4 o; o[0]=acc[dq*4]; o[1]=acc[dq*4+1]; o[2]=acc[dq*4+2]; o[3]=acc[dq*4+3];
    *(f32x4*)&gp[dq * 4] = o;
  }
  Gp[(size_t)k * 8448 + 8192 + tid] = zacc;
}

// Gfin[b][j] = sum_{i<32} Gp[b*32+i][j], b in 0..7.
__global__ __launch_bounds__(256) void reduceG(const float* __restrict__ Gp,
                                               float* __restrict__ Gfin) {
  const int o = blockIdx.x * 256 + threadIdx.x;
  if (o >= 67584) return;
  const int b = o / 8448;
  const int j = o - b * 8448;
  float s = 0.f;
  #pragma unroll 8
  for (int i = 0; i < 32; i++) s += Gp[(size_t)(b * 32 + i) * 8448 + j];
  Gfin[o] = s;
}

// kv_build (8 blocks): kv[b,h,s,d] = (sum_dd G*Wv[d,dd]) / z; block-diag KVB.
__global__ __launch_bounds__(256) void kv_build(
    const float* __restrict__ Gfin, const unsigned short* __restrict__ Wv,
    unsigned short* __restrict__ KVB)
{
  __shared__ float Gl[8192];
  __shared__ float zl[256];
  __shared__ float wvt[1024];
  const int tid = threadIdx.x;
  const int b = blockIdx.x;
  for (int i = tid; i < 8192; i += 256) Gl[i] = Gfin[(size_t)b * 8448 + i];
  zl[tid] = Gfin[(size_t)b * 8448 + 8192 + tid];
  for (int i = tid; i < 1024; i += 256) {
    const int dd = i >> 5, d = i & 31;
    wvt[i] = b2f(Wv[d * 32 + dd]);
  }
  __syncthreads();

  const int h = tid >> 5, d = tid & 31;
  unsigned short row[32];
  for (int s = 0; s < 32; s++) {
    float a = 0.f;
    #pragma unroll
    for (int dd = 0; dd < 32; dd++) a += Gl[h * 1024 + s * 32 + dd] * wvt[dd * 32 + d];
    row[s] = f2b(a / zl[h * 32 + s]);
  }
  unsigned short* out = &KVB[(size_t)b * 65536 + (size_t)(h * 32 + d) * 256 + h * 32];
  #pragma unroll
  for (int e = 0; e < 4; e++) *(u16x8*)&out[e * 8] = *(u16x8*)&row[e * 8];
}

__global__ __launch_bounds__(256) void copy_h0(const unsigned short* __restrict__ src,
                                               unsigned short* __restrict__ dst) {
  size_t i = ((size_t)blockIdx.x * 256 + threadIdx.x) * 8;
  *(u16x8*)&dst[i] = *(const u16x8*)&src[i];
}

// ---------------------------------------------------------------------------
extern "C" void kernel_launch(void* const* d_in, const int* in_sizes, int n_in,
                              void* d_out, int out_size, void* d_ws, size_t ws_size,
                              hipStream_t stream)
{
  const void* fx   = d_in[0];
  const void* ln1w = d_in[1];
  const void* ln1b = d_in[2];
  const void* Wx   = d_in[3];
  const void* bx   = d_in[4];
  const void* Wq   = d_in[5];
  const void* Wk   = d_in[6];
  const void* Wv   = d_in[7];
  const void* Wo   = d_in[8];
  const void* bo   = d_in[9];
  const void* ln2w = d_in[10];
  const void* ln2b = d_in[11];
  const void* W1   = d_in[12];
  const void* b1   = d_in[13];
  const void* W2   = d_in[14];
  const void* b2   = d_in[15];

  // ws layout (~24.7 MB)
  unsigned short* ws    = (unsigned short*)d_ws;
  unsigned short* hid   = ws;                      // 8,388,608 u16 (16 MB): h-upper copy
  float* Gp             = (float*)ws;              // overlay: 256*8448 f32 (dead by MLP)
  unsigned short* wtab  = ws + 8388608;            // 661,248 u16
  unsigned short* h0res = wtab + 661248;           // 2,097,152 u16 (4 MB)
  float* Gfin           = (float*)h0res;           // overlay: 67,584 f32
  unsigned short* Wqbig = h0res + 2097152;         // 65,536
  unsigned short* Wkbig = Wqbig + 65536;           // 65,536
  unsigned short* KVB   = Wkbig + 65536;           // 524,288
  unsigned short* zbias = KVB + 524288;            // 256
  float* fpw = (float*)(zbias + 256);
  float* mu1 = fpw;
  float* rs1 = fpw + 65536;
  float* mu2 = fpw + 131072;
  float* rs2 = fpw + 196608;
  int* flagp = (int*)(fpw + 262144);

  const int OFF_LN1W=0, OFF_LN1B=256, OFF_WX=512, OFF_BX=66048,
            OFF_WQ=66304, OFF_WK=67328, OFF_WV=68352,
            OFF_WO=69376, OFF_BO=134912, OFF_LN2W=135168, OFF_LN2B=135424,
            OFF_W1=135680, OFF_B1=397824, OFF_W2=398848, OFF_B2=660992;

  unsigned short* xm  = (unsigned short*)d_out;    // lower: xmid->qkv2d (dead after Wo)
  unsigned short* xup = xm + 16777216;             // upper: E2d->QL->Qs->h

  // 0. dtype sniff + weight table
  sniff_kernel<<<1, 64, 0, stream>>>((const unsigned*)fx, flagp);
  CvtDesc cd;
  const void* srcs[15] = {ln1w, ln1b, Wx, bx, Wq, Wk, Wv, Wo, bo, ln2w, ln2b, W1, b1, W2, b2};
  const int offs[15]   = {OFF_LN1W, OFF_LN1B, OFF_WX, OFF_BX, OFF_WQ, OFF_WK, OFF_WV,
                          OFF_WO, OFF_BO, OFF_LN2W, OFF_LN2B, OFF_W1, OFF_B1, OFF_W2, OFF_B2};
  const int ns[15]     = {256, 256, 65536, 256, 1024, 1024, 1024, 65536, 256, 256, 256,
                          262144, 1024, 262144, 256};
  for (int i = 0; i < 15; i++) { cd.src[i] = srcs[i]; cd.off[i] = offs[i]; cd.n[i] = ns[i]; }
  cvt_tab<<<dim3(1024, 15), 256, 0, stream>>>(cd, wtab, flagp);
  build_big<<<256, 256, 0, stream>>>(wtab + OFF_WQ, wtab + OFF_WK, Wqbig, Wkbig);
  zero_u16<<<257, 256, 0, stream>>>(KVB, 524544);

  // 1. LN1 stats; xmid = LN1(fx) @ Wx^T + bx -> xm
  ln_stats<<<16384, 256, 0, stream>>>(fx, flagp, 1, mu1, rs1);
  gemm_bt_ln<<<dim3(512, 2), 256, 0, stream>>>(fx, flagp, 1, mu1, rs1,
      wtab + OFF_LN1W, wtab + OFF_LN1B, wtab + OFF_WX, wtab + OFF_BX,
      xm, 256, 256, 0);

  // 2. E2d = exp(xmid @ Wkbig^T) -> xup
  gemm_bt<<<dim3(512, 2), 256, 0, stream>>>(xm, Wkbig, zbias, nullptr, flagp,
                                            xup, 256, 256, 2, 0, 0);

  // 3. G partials + reduce; kv -> KVB block-diag
  accumG<<<256, 256, 0, stream>>>(xm, xup, Gp);
  reduceG<<<264, 256, 0, stream>>>(Gp, Gfin);
  kv_build<<<8, 256, 0, stream>>>(Gfin, wtab + OFF_WV, KVB);

  // 4. Qs = segsoftmax(xmid @ Wqbig^T) -> xup (E2d dead), fused in epilogue
  gemm_bt<<<dim3(512, 2), 256, 0, stream>>>(xm, Wqbig, zbias, nullptr, flagp,
                                            xup, 256, 256, 3, 0, 0);

  // 5. qkv2d = Qs @ KVB[b]^T -> xm (xmid dead), z-batched over b
  gemm_bt<<<dim3(64, 2, 8), 256, 0, stream>>>(xup, KVB, zbias, nullptr, flagp,
                                              xm, 256, 256, 0, 8192, 65536);

  // 6. h = qkv2d @ Wo^T + bo + fx -> xup (Qs dead; NOT in-place -> full grid)
  gemm_bt<<<dim3(512, 2), 256, 0, stream>>>(xm, wtab + OFF_WO, wtab + OFF_BO, fx, flagp,
                                            xup, 256, 256, 0, 0, 0);

  // 7. LN2 stats on h; copy h rows [32768,65536) -> ws hid area (Gp dead).
  //    Launch 1 (rows<32768) writes only dead xm bytes; launch 2 reads only
  //    the copy -> no write-order hazard anywhere.
  ln_stats<<<16384, 256, 0, stream>>>(xup, flagp, 0, mu2, rs2);
  copy_h0<<<4096, 256, 0, stream>>>(xup + (size_t)32768 * 256, hid);

  // 8. fused MLP: y = GELU(LN2(h)@W1^T+b1)@W2^T + b2 + h
  fused_mlp<<<512, 256, 0, stream>>>(xup, mu2, rs2,
      wtab + OFF_LN2W, wtab + OFF_LN2B, wtab + OFF_W1, wtab + OFF_B1,
      wtab + OFF_W2, wtab + OFF_B2, d_out, flagp, 0L);
  fused_mlp<<<512, 256, 0, stream>>>(hid, mu2 + 32768, rs2 + 32768,
      wtab + OFF_LN2W, wtab + OFF_LN2B, wtab + OFF_W1, wtab + OFF_B1,
      wtab + OFF_W2, wtab + OFF_B2, d_out, flagp, 32768L);
}

// Round 3
// 487.421 us; speedup vs baseline: 1.5422x; 1.0407x over previous
//
#include <hip/hip_runtime.h>
#include <math.h>

// ---------------------------------------------------------------------------
// LinearNO block, MI355X/gfx950. Inputs fp32 (sniffed; bf16 fallback).
// Interior bf16 MFMA. B=8 N=8192 C=256 H=8 D=32 S=32.
//
// R10 changes vs R9 (507 us):
//  * fused_mlp rewritten:
//    - GEMM1 computes tT = W1c @ lnA^T, so LN2(h) lives in per-lane REGISTER
//      fragments (loaded+LN'd once, reused all 32 chunks). No lnA LDS.
//    - tT C-frag holds 4 consecutive hid per token -> per-wave t tile
//      [tok][hid] written as 2x ds_write_b64, read as 1x ds_read_b128.
//      Intra-wave only: no barriers for the t exchange (lgkmcnt only).
//    - W1c/W2c double-buffered in LDS, staged for c+1 at loop top; ONE
//      s_barrier per chunk (was 4 + vmcnt0 drain).
//    - t stride 80 B (bank-coprime); W2 row-XOR swizzle; packed t writes.
//    - GELU via A&S 7.1.26 erf poly (|eps|<=1.5e-7, ~2.5x cheaper than erff).
// ---------------------------------------------------------------------------

typedef __attribute__((ext_vector_type(8))) short bf8;
typedef __attribute__((ext_vector_type(4))) float f32x4;
typedef __attribute__((ext_vector_type(4))) unsigned short u16x4;
typedef __attribute__((ext_vector_type(8))) unsigned short u16x8;

__device__ __forceinline__ float b2f(unsigned short x) {
  union { unsigned u; float f; } t; t.u = ((unsigned)x) << 16; return t.f;
}
__device__ __forceinline__ unsigned short f2b(float f) {
  union { float f; unsigned u; } t; t.f = f;
  unsigned r = t.u + 0x7fffu + ((t.u >> 16) & 1u);
  return (unsigned short)(r >> 16);
}
__device__ __forceinline__ float gelu_exact(float x) {
  return 0.5f * x * (1.0f + erff(x * 0.7071067811865475f));
}
// A&S 7.1.26 erf, |eps| <= 1.5e-7 (abs). Much cheaper than libm erff.
__device__ __forceinline__ float erf_fast(float x) {
  float ax = fabsf(x);
  float t = __builtin_amdgcn_rcpf(fmaf(0.3275911f, ax, 1.0f));
  float p = t * fmaf(t, fmaf(t, fmaf(t, fmaf(t, 1.061405429f, -1.453152027f),
                                     1.421413741f), -0.284496736f), 0.254829592f);
  float r = 1.0f - p * __expf(-ax * ax);
  return copysignf(r, x);
}
__device__ __forceinline__ float gelu_fast(float x) {
  return 0.5f * x * (1.0f + erf_fast(x * 0.7071067811865475f));
}

// async global->LDS, 16 B per lane. LDS dest must be base + lane*16.
typedef __attribute__((address_space(1))) const void gas_void;
typedef __attribute__((address_space(3))) void las_void;
__device__ __forceinline__ void gl_lds16(const void* g, void* l) {
  __builtin_amdgcn_global_load_lds((gas_void*)g, (las_void*)l, 16, 0, 0);
}

// --------------------------- dtype sniffer ---------------------------------
__global__ void sniff_kernel(const unsigned* __restrict__ fx, int* __restrict__ flag) {
  if (threadIdx.x == 0) {
    int cnt = 0;
    for (int i = 0; i < 64; i++) {
      unsigned e = (fx[i] >> 7) & 0xFFu;
      cnt += (e >= 117u && e <= 130u) ? 1 : 0;
    }
    *flag = (cnt >= 32) ? 1 : 0;   // 1 = bf16 inputs, 0 = fp32
  }
}

// --------------------------- weight table ----------------------------------
struct CvtDesc { const void* src[15]; int off[15]; int n[15]; };

__global__ __launch_bounds__(256) void cvt_tab(CvtDesc d, unsigned short* __restrict__ wtab,
                                               const int* __restrict__ flagp) {
  const int seg = blockIdx.y;
  const int i = blockIdx.x * 256 + threadIdx.x;
  if (i >= d.n[seg]) return;
  unsigned short o;
  if (*flagp) o = ((const unsigned short*)d.src[seg])[i];
  else        o = f2b(((const float*)d.src[seg])[i]);
  wtab[d.off[seg] + i] = o;
}

// Block-diagonal Wq_big / Wk_big [256,256]: big[h*32+s][h*32+d]=W[s][d].
__global__ __launch_bounds__(256) void build_big(
    const unsigned short* __restrict__ wq, const unsigned short* __restrict__ wk,
    unsigned short* __restrict__ Wqbig, unsigned short* __restrict__ Wkbig)
{
  const int idx = blockIdx.x * 256 + threadIdx.x;
  const int row = idx >> 8, col = idx & 255;
  const bool same = (row >> 5) == (col >> 5);
  const int wi = (row & 31) * 32 + (col & 31);
  Wqbig[idx] = same ? wq[wi] : (unsigned short)0;
  Wkbig[idx] = same ? wk[wi] : (unsigned short)0;
}

__global__ __launch_bounds__(256) void zero_u16(unsigned short* __restrict__ p, int n) {
  int i8 = (blockIdx.x * 256 + threadIdx.x) * 8;
  if (i8 < n) { u16x8 z = {}; *(u16x8*)&p[i8] = z; }
}

// --------------------------- LN stats --------------------------------------
__global__ __launch_bounds__(256) void ln_stats(
    const void* __restrict__ X, const int* __restrict__ flagp, int amode,
    float* __restrict__ MU, float* __restrict__ RS)
{
  const int lane = threadIdx.x & 63;
  const int wave = threadIdx.x >> 6;
  const size_t row = (size_t)blockIdx.x * 4 + wave;
  const size_t base = row * 256 + lane * 4;
  const bool abf = amode ? ((*flagp) != 0) : true;
  float x0, x1, x2, x3;
  if (abf) {
    u16x4 uv = *(const u16x4*)&((const unsigned short*)X)[base];
    x0 = b2f(uv[0]); x1 = b2f(uv[1]); x2 = b2f(uv[2]); x3 = b2f(uv[3]);
  } else {
    f32x4 t = *(const f32x4*)&((const float*)X)[base];
    x0 = t[0]; x1 = t[1]; x2 = t[2]; x3 = t[3];
  }
  float s = x0 + x1 + x2 + x3;
  float q = x0*x0 + x1*x1 + x2*x2 + x3*x3;
  #pragma unroll
  for (int m = 1; m < 64; m <<= 1) { s += __shfl_xor(s, m, 64); q += __shfl_xor(q, m, 64); }
  float mean = s * (1.0f / 256.0f);
  float var  = q * (1.0f / 256.0f) - mean * mean;
  if (lane == 0) { MU[row] = mean; RS[row] = rsqrtf(var + 1e-5f); }
}

// --------------------------- generic MFMA GEMM (pipelined) ------------------
// Y[.,N] = A @ W^T + bias (+Res dtype-branched) ; act: 0 none, 2 exp,
// 3 segment-softmax (32-col segments, fused jax.nn.softmax over slices).
// 128x128 tile; 3-slot LDS ring, stage t+2 while computing t, counted vmcnt.
// z-batch: rows += z*mz, W += z*wz.
__global__ __launch_bounds__(256) void gemm_bt(
    const unsigned short* __restrict__ A,
    const unsigned short* __restrict__ W,
    const unsigned short* __restrict__ bias,
    const void* __restrict__ Res, const int* __restrict__ flagp,
    unsigned short* __restrict__ Y,
    int N, int K, int act, int mz, long wz)
{
  __shared__ __align__(16) unsigned short smem[3 * 8192];   // 48 KB ring
  const int tid = threadIdx.x, lane = tid & 63, wave = tid >> 6;
  const size_t zrow = (size_t)blockIdx.z * mz;
  const int bm = blockIdx.x * 128, bn = blockIdx.y * 128;
  const int wm = (wave >> 1) * 64, wn = (wave & 1) * 64;
  const int quad = lane >> 4, l16 = lane & 15;
  const unsigned short* Wz = W + (size_t)blockIdx.z * wz;

  f32x4 acc[4][4] = {};
  const int r0 = tid >> 2;
  const int co = (tid & 3) * 8;
  const unsigned short* pa0 = &A[(zrow + bm + r0) * K + co];
  const unsigned short* pa1 = &A[(zrow + bm + r0 + 64) * K + co];
  const unsigned short* pb0 = &Wz[(size_t)(bn + r0) * K + co];
  const unsigned short* pb1 = &Wz[(size_t)(bn + r0 + 64) * K + co];
  const int nt = K >> 5;

  auto stage = [&](int t, int sl) {
    const int k0 = t << 5;
    unsigned short* b_ = &smem[sl * 8192 + tid * 8];
    gl_lds16(pa0 + k0, b_);
    gl_lds16(pa1 + k0, b_ + 2048);
    gl_lds16(pb0 + k0, b_ + 4096);
    gl_lds16(pb1 + k0, b_ + 6144);
  };

  stage(0, 0);
  if (nt > 1) stage(1, 1);
  int scur = 0, snew = 2;
  for (int t = 0; t < nt; ++t) {
    if (t + 2 < nt) {
      stage(t + 2, snew);
      asm volatile("s_waitcnt vmcnt(8)" ::: "memory");   // tile t landed (mine)
    } else if (t + 1 < nt) {
      asm volatile("s_waitcnt vmcnt(4)" ::: "memory");
    } else {
      asm volatile("s_waitcnt vmcnt(0)" ::: "memory");
    }
    __builtin_amdgcn_s_barrier();                        // tile t landed (all)
    __builtin_amdgcn_sched_barrier(0);

    const unsigned short* sa = &smem[scur * 8192];
    const unsigned short* sb = sa + 4096;
    bf8 af[4], bfr[4];
    #pragma unroll
    for (int i = 0; i < 4; i++) af[i]  = *(const bf8*)&sa[(wm + i * 16 + l16) * 32 + quad * 8];
    #pragma unroll
    for (int j = 0; j < 4; j++) bfr[j] = *(const bf8*)&sb[(wn + j * 16 + l16) * 32 + quad * 8];
    #pragma unroll
    for (int i = 0; i < 4; i++)
      #pragma unroll
      for (int j = 0; j < 4; j++)
        acc[i][j] = __builtin_amdgcn_mfma_f32_16x16x32_bf16(af[i], bfr[j], acc[i][j], 0, 0, 0);

    __builtin_amdgcn_sched_barrier(0);
    __builtin_amdgcn_s_barrier();                        // all waves done reading slot
    scur = scur + 1 < 3 ? scur + 1 : 0;
    snew = snew + 1 < 3 ? snew + 1 : 0;
  }

  // ---- epilogue: bias/act in registers, f32 tile via LDS, coalesced stores
  const bool rbf = Res ? ((*flagp) != 0) : true;
  float bv[4];
  #pragma unroll
  for (int j = 0; j < 4; j++) bv[j] = b2f(bias[bn + wn + j * 16 + l16]);
  #pragma unroll
  for (int i = 0; i < 4; i++)
    #pragma unroll
    for (int j = 0; j < 4; j++)
      #pragma unroll
      for (int r = 0; r < 4; r++) {
        float v = acc[i][j][r] + bv[j];
        if (act == 2) v = __expf(v);
        acc[i][j][r] = v;
      }
  if (act == 3) {
    #pragma unroll
    for (int i = 0; i < 4; i++)
      #pragma unroll
      for (int g = 0; g < 2; g++)
        #pragma unroll
        for (int r = 0; r < 4; r++) {
          float a0 = acc[i][2*g][r], a1 = acc[i][2*g+1][r];
          float m = fmaxf(a0, a1);
          #pragma unroll
          for (int msk = 1; msk < 16; msk <<= 1) m = fmaxf(m, __shfl_xor(m, msk, 64));
          float e0 = __expf(a0 - m), e1 = __expf(a1 - m);
          float s = e0 + e1;
          #pragma unroll
          for (int msk = 1; msk < 16; msk <<= 1) s += __shfl_xor(s, msk, 64);
          const float rz = 1.0f / s;
          acc[i][2*g][r] = e0 * rz; acc[i][2*g+1][r] = e1 * rz;
        }
  }

  float* cf = (float*)smem;              // 64x128 f32 half-tile (32 KB)
  const int whalf = wm >> 6;
  #pragma unroll
  for (int half = 0; half < 2; ++half) {
    __builtin_amdgcn_s_barrier();
    if (whalf == half) {
      #pragma unroll
      for (int i = 0; i < 4; i++)
        #pragma unroll
        for (int j = 0; j < 4; j++)
          #pragma unroll
          for (int r = 0; r < 4; r++)
            cf[(i * 16 + quad * 4 + r) * 128 + wn + j * 16 + l16] = acc[i][j][r];
    }
    __builtin_amdgcn_s_barrier();
    #pragma unroll
    for (int st = 0; st < 4; ++st) {
      const int e = st * 2048 + tid * 8;
      const int row = e >> 7;
      const size_t gbase = (zrow + bm + half * 64 + row) * (size_t)N + bn + (e & 127);
      float v[8];
      #pragma unroll
      for (int u = 0; u < 8; u++) v[u] = cf[e + u];
      if (Res) {
        if (rbf) {
          u16x8 rv = *(const u16x8*)&((const unsigned short*)Res)[gbase];
          #pragma unroll
          for (int u = 0; u < 8; u++) v[u] += b2f(rv[u]);
        } else {
          f32x4 ra = *(const f32x4*)&((const float*)Res)[gbase];
          f32x4 rb = *(const f32x4*)&((const float*)Res)[gbase + 4];
          v[0] += ra[0]; v[1] += ra[1]; v[2] += ra[2]; v[3] += ra[3];
          v[4] += rb[0]; v[5] += rb[1]; v[6] += rb[2]; v[7] += rb[3];
        }
      }
      u16x8 o;
      #pragma unroll
      for (int u = 0; u < 8; u++) o[u] = f2b(v[u]);
      *(u16x8*)&Y[gbase] = o;
    }
  }
}

// GEMM with LN applied to A during staging (amode: 1=flag dtype, 0=bf16);
// B side uses DMA staging. act=1 -> GELU. Coalesced LDS epilogue.
__global__ __launch_bounds__(256) void gemm_bt_ln(
    const void* __restrict__ A, const int* __restrict__ flagp, int amode,
    const float* __restrict__ MU, const float* __restrict__ RS,
    const unsigned short* __restrict__ lw, const unsigned short* __restrict__ lb,
    const unsigned short* __restrict__ W, const unsigned short* __restrict__ bias,
    unsigned short* __restrict__ Y, int N, int K, int act)
{
  __shared__ __align__(16) unsigned char smemc[32768];       // lA+lB, cf overlay
  unsigned short* lA = (unsigned short*)smemc;
  unsigned short* lB = lA + 4096;
  const int tid = threadIdx.x, lane = tid & 63, wave = tid >> 6;
  const int bm = blockIdx.x * 128, bn = blockIdx.y * 128;
  const int wm = (wave >> 1) * 64, wn = (wave & 1) * 64;
  const int quad = lane >> 4, l16 = lane & 15;
  const bool abf = amode ? ((*flagp) != 0) : true;
  const unsigned short* Ab = (const unsigned short*)A;
  const float* Af = (const float*)A;

  f32x4 acc[4][4] = {};
  const int r0 = tid >> 2;
  const int co = (tid & 3) * 8;
  const unsigned short* pb0 = &W[(size_t)(bn + r0) * K + co];
  const unsigned short* pb1 = &W[(size_t)(bn + r0 + 64) * K + co];

  for (int k0 = 0; k0 < K; k0 += 32) {
    u16x8 wv8 = *(const u16x8*)&lw[k0 + co];
    u16x8 bv8 = *(const u16x8*)&lb[k0 + co];
    __syncthreads();
    gl_lds16(pb0 + k0, &lB[tid * 8]);
    gl_lds16(pb1 + k0, &lB[2048 + tid * 8]);
    #pragma unroll
    for (int half = 0; half < 2; half++) {
      const int ar = bm + r0 + half * 64;
      const float m_ = MU[ar], r_ = RS[ar];
      float xv[8];
      if (abf) {
        u16x8 t = *(const u16x8*)&Ab[(size_t)ar * K + k0 + co];
        #pragma unroll
        for (int e = 0; e < 8; e++) xv[e] = b2f(t[e]);
      } else {
        f32x4 t0 = *(const f32x4*)&Af[(size_t)ar * K + k0 + co];
        f32x4 t1 = *(const f32x4*)&Af[(size_t)ar * K + k0 + co + 4];
        xv[0]=t0[0]; xv[1]=t0[1]; xv[2]=t0[2]; xv[3]=t0[3];
        xv[4]=t1[0]; xv[5]=t1[1]; xv[6]=t1[2]; xv[7]=t1[3];
      }
      u16x8 o;
      #pragma unroll
      for (int e = 0; e < 8; e++)
        o[e] = f2b((xv[e] - m_) * r_ * b2f(wv8[e]) + b2f(bv8[e]));
      *(u16x8*)&lA[half * 2048 + tid * 8] = o;
    }
    __syncthreads();

    bf8 af[4], bfr[4];
    #pragma unroll
    for (int i = 0; i < 4; i++) af[i]  = *(const bf8*)&lA[(wm + i * 16 + l16) * 32 + quad * 8];
    #pragma unroll
    for (int j = 0; j < 4; j++) bfr[j] = *(const bf8*)&lB[(wn + j * 16 + l16) * 32 + quad * 8];
    #pragma unroll
    for (int i = 0; i < 4; i++)
      #pragma unroll
      for (int j = 0; j < 4; j++)
        acc[i][j] = __builtin_amdgcn_mfma_f32_16x16x32_bf16(af[i], bfr[j], acc[i][j], 0, 0, 0);
  }

  // epilogue: bias + act in registers, coalesced store via LDS f32 tile
  float bv[4];
  #pragma unroll
  for (int j = 0; j < 4; j++) bv[j] = b2f(bias[bn + wn + j * 16 + l16]);
  #pragma unroll
  for (int i = 0; i < 4; i++)
    #pragma unroll
    for (int j = 0; j < 4; j++)
      #pragma unroll
      for (int r = 0; r < 4; r++) {
        float v = acc[i][j][r] + bv[j];
        if (act) v = gelu_exact(v);
        acc[i][j][r] = v;
      }

  float* cf = (float*)smemc;
  const int whalf = wm >> 6;
  #pragma unroll
  for (int half = 0; half < 2; ++half) {
    __syncthreads();
    if (whalf == half) {
      #pragma unroll
      for (int i = 0; i < 4; i++)
        #pragma unroll
        for (int j = 0; j < 4; j++)
          #pragma unroll
          for (int r = 0; r < 4; r++)
            cf[(i * 16 + quad * 4 + r) * 128 + wn + j * 16 + l16] = acc[i][j][r];
    }
    __syncthreads();
    #pragma unroll
    for (int st = 0; st < 4; ++st) {
      const int e = st * 2048 + tid * 8;
      const int row = e >> 7;
      const size_t gbase = (size_t)(bm + half * 64 + row) * N + bn + (e & 127);
      u16x8 o;
      #pragma unroll
      for (int u = 0; u < 8; u++) o[u] = f2b(cf[e + u]);
      *(u16x8*)&Y[gbase] = o;
    }
  }
}

// ---------------------------------------------------------------------------
// fused_mlp v2: per 64-row block, y = GELU(LN2(h)@W1^T+b1)@W2^T + b2 + h.
// Wave w owns output rows [w*16, w*16+16), all 256 cols (acc: 16 f32x4).
// LN2(h) A-fragments live in registers (8 bf8/lane, loaded once).
// Per chunk c (32 hid): GEMM1 tT = W1c @ lnA^T (16 MFMA) -> GELU in regs ->
// per-wave t[tok][hid] LDS tile (2x ds_write_b64 / 1x ds_read_b128, no
// barriers) -> GEMM2 acc += t @ W2c^T (16 MFMA). W1c/W2c double-buffered,
// staged for c+1 at loop top via gl_lds16; ONE s_barrier per chunk.
// LDS: W1 dbuf 32K | W2 dbuf 32K @32768 | t 4x1280 @65536 = 70656 B.
// cf epilogue overlays bytes [0,65536).
// ---------------------------------------------------------------------------
__global__ __launch_bounds__(256) void fused_mlp(
    const unsigned short* __restrict__ Hsrc,
    const float* __restrict__ MU, const float* __restrict__ RS,
    const unsigned short* __restrict__ lw, const unsigned short* __restrict__ lb,
    const unsigned short* __restrict__ W1, const unsigned short* __restrict__ bs1,
    const unsigned short* __restrict__ W2, const unsigned short* __restrict__ bs2,
    void* __restrict__ OUT, const int* __restrict__ flagp, long row0)
{
  __shared__ __align__(16) unsigned char smem[70656];
  const int tid = threadIdx.x, lane = tid & 63, wave = tid >> 6;
  const int quad = lane >> 4, l16 = lane & 15;
  const int brow = blockIdx.x * 64;

  auto stageW1 = [&](int c, int b) {
    const unsigned short* src = W1 + (size_t)c * 8192;   // 32 hid-rows x 256
    unsigned char* dst = smem + b * 16384;
    #pragma unroll
    for (int s = 0; s < 4; s++) {
      const int unit = s * 256 + tid;
      const int row = unit >> 5, u = unit & 31;
      gl_lds16(src + row * 256 + ((u ^ (row & 7)) * 8), dst + unit * 16);
    }
  };
  auto stageW2 = [&](int c, int b) {
    const unsigned short* src = W2 + c * 32;             // 256 rows x 32 (of 1024)
    unsigned char* dst = smem + 32768 + b * 16384;
    #pragma unroll
    for (int s = 0; s < 4; s++) {
      const int unit = s * 256 + tid;
      const int row = unit >> 2, u = unit & 3;
      gl_lds16(src + (size_t)row * 1024 + ((u ^ ((row >> 1) & 3)) * 8), dst + unit * 16);
    }
  };

  stageW1(0, 0);
  stageW2(0, 0);

  // ---- LN2(h) A-fragments in registers: lane (q,l16) holds row w*16+l16,
  //      cols ks*32 + q*8 .. +7 for ks = 0..7.
  const int myrow = wave * 16 + l16;
  const float m_ = MU[brow + myrow], r_ = RS[brow + myrow];
  const unsigned short* hr = Hsrc + (size_t)(brow + myrow) * 256 + quad * 8;
  bf8 areg[8];
  #pragma unroll
  for (int ks = 0; ks < 8; ks++) {
    u16x8 hv = *(const u16x8*)&hr[ks * 32];
    u16x8 wv = *(const u16x8*)&lw[ks * 32 + quad * 8];
    u16x8 bv = *(const u16x8*)&lb[ks * 32 + quad * 8];
    u16x8 o;
    #pragma unroll
    for (int e = 0; e < 8; e++)
      o[e] = f2b((b2f(hv[e]) - m_) * r_ * b2f(wv[e]) + b2f(bv[e]));
    *(u16x8*)&areg[ks] = o;
  }

  asm volatile("s_waitcnt vmcnt(0)" ::: "memory");   // chunk-0 W landed (mine)
  __builtin_amdgcn_s_barrier();                      // (all)

  f32x4 acc[16] = {};
  unsigned short* tw = (unsigned short*)(smem + 65536 + wave * 1280);
  const int gsw = (l16 >> 1) & 3;                    // W2 read swizzle
  int bsel = 0;

  for (int c = 0; c < 32; ++c) {
    if (c + 1 < 32) {
      stageW1(c + 1, bsel ^ 1);
      stageW2(c + 1, bsel ^ 1);
      __builtin_amdgcn_sched_barrier(0);
    }

    // ---- GEMM1: tT[32 hid x 16 tok] = W1c @ lnA^T
    const unsigned short* w1b = (const unsigned short*)(smem + bsel * 16384);
    f32x4 p0 = {}, p1 = {};
    #pragma unroll
    for (int ks = 0; ks < 8; ks++) {
      const int slot = (ks * 4 + quad) ^ (l16 & 7);
      bf8 a0, a1;
      *(u16x8*)&a0 = *(const u16x8*)&w1b[l16 * 256 + slot * 8];
      *(u16x8*)&a1 = *(const u16x8*)&w1b[(16 + l16) * 256 + slot * 8];
      p0 = __builtin_amdgcn_mfma_f32_16x16x32_bf16(a0, areg[ks], p0, 0, 0, 0);
      p1 = __builtin_amdgcn_mfma_f32_16x16x32_bf16(a1, areg[ks], p1, 0, 0, 0);
    }

    // ---- bias + GELU in regs; pack 4 consecutive hid -> one ds_write_b64.
    // lane (q,l16) holds tT rows (hid) i*16+q*4+r, col (tok) l16.
    {
      u16x4 bv0 = *(const u16x4*)&bs1[c * 32 + quad * 4];
      u16x4 bv1 = *(const u16x4*)&bs1[c * 32 + 16 + quad * 4];
      u16x4 o0, o1;
      #pragma unroll
      for (int r = 0; r < 4; r++) {
        o0[r] = f2b(gelu_fast(p0[r] + b2f(bv0[r])));
        o1[r] = f2b(gelu_fast(p1[r] + b2f(bv1[r])));
      }
      // t layout: [tok l16][hid 32] stride 80 B (40 u16)
      *(u16x4*)&tw[l16 * 40 + quad * 4]      = o0;
      *(u16x4*)&tw[l16 * 40 + 16 + quad * 4] = o1;
    }
    asm volatile("s_waitcnt lgkmcnt(0)" ::: "memory");   // t visible (intra-wave)
    __builtin_amdgcn_sched_barrier(0);

    // ---- GEMM2: acc[16 tok x 256 out] += t @ W2c^T
    bf8 ta;
    *(u16x8*)&ta = *(const u16x8*)&tw[l16 * 40 + quad * 8];
    const unsigned short* w2b = (const unsigned short*)(smem + 32768 + bsel * 16384);
    #pragma unroll
    for (int j = 0; j < 16; j++) {
      bf8 bw;
      *(u16x8*)&bw = *(const u16x8*)&w2b[(j * 16 + l16) * 32 + ((quad ^ gsw) * 8)];
      acc[j] = __builtin_amdgcn_mfma_f32_16x16x32_bf16(ta, bw, acc[j], 0, 0, 0);
    }

    asm volatile("s_waitcnt vmcnt(0)" ::: "memory");   // my c+1 staging landed
    __builtin_amdgcn_s_barrier();                      // all reads of bsel done, c+1 ready
    bsel ^= 1;
  }

  // ---- epilogue: acc -> cf [64][256] f32 (overlays W bufs), coalesced store
  float* cf = (float*)smem;
  #pragma unroll
  for (int j = 0; j < 16; j++)
    #pragma unroll
    for (int r = 0; r < 4; r++)
      cf[(wave * 16 + quad * 4 + r) * 256 + j * 16 + l16] = acc[j][r];
  __syncthreads();

  const bool obf = (*flagp) != 0;
  const unsigned short* hrow = Hsrc + (size_t)brow * 256;
  #pragma unroll
  for (int s = 0; s < 8; s++) {
    const int e = s * 2048 + tid * 8;
    const int row = e >> 8, col = e & 255;
    u16x8 rv = *(const u16x8*)&hrow[e];
    u16x8 b2v = *(const u16x8*)&bs2[col];
    float v[8];
    #pragma unroll
    for (int u = 0; u < 8; u++) v[u] = cf[e + u] + b2f(rv[u]) + b2f(b2v[u]);
    const size_t ob = (size_t)(row0 + brow + row) * 256 + col;
    if (obf) {
      u16x8 o;
      #pragma unroll
      for (int u = 0; u < 8; u++) o[u] = f2b(v[u]);
      *(u16x8*)&((unsigned short*)OUT)[ob] = o;
    } else {
      f32x4 oa, obv;
      oa[0]=v[0]; oa[1]=v[1]; oa[2]=v[2]; oa[3]=v[3];
      obv[0]=v[4]; obv[1]=v[5]; obv[2]=v[6]; obv[3]=v[7];
      *(f32x4*)&((float*)OUT)[ob] = oa;
      *(f32x4*)&((float*)OUT)[ob + 4] = obv;
    }
  }
}

// ---------------------------------------------------------------------------
// accumG: per 256-token block k: partial G[h,s,d] = sum_n E[n,h*32+s]*X[n,h*32+d]
// (+ z partial at [8192+tid]). Batch b owns blocks k = b*32 .. b*32+31.
// ---------------------------------------------------------------------------
__global__ __launch_bounds__(256) void accumG(
    const unsigned short* __restrict__ X,
    const unsigned short* __restrict__ E,
    float* __restrict__ Gp)                 // [256][8448]
{
  __shared__ float Xl[64 * 256];                         // 64 KB
  __shared__ __align__(16) unsigned short El[64 * 256];  // 32 KB
  const int tid = threadIdx.x;
  const int k = blockIdx.x;
  const int h = tid >> 5, s = tid & 31;

  float acc[32];
  #pragma unroll
  for (int d = 0; d < 32; d++) acc[d] = 0.f;
  float zacc = 0.f;

  for (int sub = 0; sub < 4; sub++) {
    const size_t r0s = (size_t)k * 256 + sub * 64;
    __syncthreads();
    #pragma unroll
    for (int i = 0; i < 8; i++) {
      const int flat = i * 2048 + tid * 8;
      u16x8 xv = *(const u16x8*)&X[r0s * 256 + flat];
      #pragma unroll
      for (int e = 0; e < 8; e++) Xl[flat + e] = b2f(xv[e]);
      *(u16x8*)&El[flat] = *(const u16x8*)&E[r0s * 256 + flat];
    }
    __syncthreads();

    for (int t = 0; t < 64; t++) {
      const float e = b2f(El[t * 256 + h * 32 + s]);
      zacc += e;
      const int xb = t * 256 + h * 32;
      #pragma unroll
      for (int dq = 0; dq < 8; dq++) {
        f32x4 xv = *(const f32x4*)&Xl[xb + dq * 4];
        acc[dq*4+0] += e * xv[0];
        acc[dq*4+1] += e * xv[1];
        acc[dq*4+2] += e * xv[2];
        acc[dq*4+3] += e * xv[3];
      }
    }
  }

  float* gp = &Gp[(size_t)k * 8448 + (size_t)tid * 32];
  #pragma unroll
  for (int dq = 0; dq < 8; dq++) {
    f32x4 o; o[0]=acc[dq*4]; o[1]=acc[dq*4+1]; o[2]=acc[dq*4+2]; o[3]=acc[dq*4+3];
    *(f32x4*)&gp[dq * 4] = o;
  }
  Gp[(size_t)k * 8448 + 8192 + tid] = zacc;
}

// Gfin[b][j] = sum_{i<32} Gp[b*32+i][j], b in 0..7.
__global__ __launch_bounds__(256) void reduceG(const float* __restrict__ Gp,
                                               float* __restrict__ Gfin) {
  const int o = blockIdx.x * 256 + threadIdx.x;
  if (o >= 67584) return;
  const int b = o / 8448;
  const int j = o - b * 8448;
  float s = 0.f;
  #pragma unroll 8
  for (int i = 0; i < 32; i++) s += Gp[(size_t)(b * 32 + i) * 8448 + j];
  Gfin[o] = s;
}

// kv_build (8 blocks): kv[b,h,s,d] = (sum_dd G*Wv[d,dd]) / z; block-diag KVB.
__global__ __launch_bounds__(256) void kv_build(
    const float* __restrict__ Gfin, const unsigned short* __restrict__ Wv,
    unsigned short* __restrict__ KVB)
{
  __shared__ float Gl[8192];
  __shared__ float zl[256];
  __shared__ float wvt[1024];
  const int tid = threadIdx.x;
  const int b = blockIdx.x;
  for (int i = tid; i < 8192; i += 256) Gl[i] = Gfin[(size_t)b * 8448 + i];
  zl[tid] = Gfin[(size_t)b * 8448 + 8192 + tid];
  for (int i = tid; i < 1024; i += 256) {
    const int dd = i >> 5, d = i & 31;
    wvt[i] = b2f(Wv[d * 32 + dd]);
  }
  __syncthreads();

  const int h = tid >> 5, d = tid & 31;
  unsigned short row[32];
  for (int s = 0; s < 32; s++) {
    float a = 0.f;
    #pragma unroll
    for (int dd = 0; dd < 32; dd++) a += Gl[h * 1024 + s * 32 + dd] * wvt[dd * 32 + d];
    row[s] = f2b(a / zl[h * 32 + s]);
  }
  unsigned short* out = &KVB[(size_t)b * 65536 + (size_t)(h * 32 + d) * 256 + h * 32];
  #pragma unroll
  for (int e = 0; e < 4; e++) *(u16x8*)&out[e * 8] = *(u16x8*)&row[e * 8];
}

__global__ __launch_bounds__(256) void copy_h0(const unsigned short* __restrict__ src,
                                               unsigned short* __restrict__ dst) {
  size_t i = ((size_t)blockIdx.x * 256 + threadIdx.x) * 8;
  *(u16x8*)&dst[i] = *(const u16x8*)&src[i];
}

// ---------------------------------------------------------------------------
extern "C" void kernel_launch(void* const* d_in, const int* in_sizes, int n_in,
                              void* d_out, int out_size, void* d_ws, size_t ws_size,
                              hipStream_t stream)
{
  const void* fx   = d_in[0];
  const void* ln1w = d_in[1];
  const void* ln1b = d_in[2];
  const void* Wx   = d_in[3];
  const void* bx   = d_in[4];
  const void* Wq   = d_in[5];
  const void* Wk   = d_in[6];
  const void* Wv   = d_in[7];
  const void* Wo   = d_in[8];
  const void* bo   = d_in[9];
  const void* ln2w = d_in[10];
  const void* ln2b = d_in[11];
  const void* W1   = d_in[12];
  const void* b1   = d_in[13];
  const void* W2   = d_in[14];
  const void* b2   = d_in[15];

  // ws layout (~24.7 MB)
  unsigned short* ws    = (unsigned short*)d_ws;
  unsigned short* hid   = ws;                      // 8,388,608 u16 (16 MB): h-upper copy
  float* Gp             = (float*)ws;              // overlay: 256*8448 f32 (dead by MLP)
  unsigned short* wtab  = ws + 8388608;            // 661,248 u16
  unsigned short* h0res = wtab + 661248;           // 2,097,152 u16 (4 MB)
  float* Gfin           = (float*)h0res;           // overlay: 67,584 f32
  unsigned short* Wqbig = h0res + 2097152;         // 65,536
  unsigned short* Wkbig = Wqbig + 65536;           // 65,536
  unsigned short* KVB   = Wkbig + 65536;           // 524,288
  unsigned short* zbias = KVB + 524288;            // 256
  float* fpw = (float*)(zbias + 256);
  float* mu1 = fpw;
  float* rs1 = fpw + 65536;
  float* mu2 = fpw + 131072;
  float* rs2 = fpw + 196608;
  int* flagp = (int*)(fpw + 262144);

  const int OFF_LN1W=0, OFF_LN1B=256, OFF_WX=512, OFF_BX=66048,
            OFF_WQ=66304, OFF_WK=67328, OFF_WV=68352,
            OFF_WO=69376, OFF_BO=134912, OFF_LN2W=135168, OFF_LN2B=135424,
            OFF_W1=135680, OFF_B1=397824, OFF_W2=398848, OFF_B2=660992;

  unsigned short* xm  = (unsigned short*)d_out;    // lower: xmid->qkv2d (dead after Wo)
  unsigned short* xup = xm + 16777216;             // upper: E2d->QL->Qs->h

  // 0. dtype sniff + weight table
  sniff_kernel<<<1, 64, 0, stream>>>((const unsigned*)fx, flagp);
  CvtDesc cd;
  const void* srcs[15] = {ln1w, ln1b, Wx, bx, Wq, Wk, Wv, Wo, bo, ln2w, ln2b, W1, b1, W2, b2};
  const int offs[15]   = {OFF_LN1W, OFF_LN1B, OFF_WX, OFF_BX, OFF_WQ, OFF_WK, OFF_WV,
                          OFF_WO, OFF_BO, OFF_LN2W, OFF_LN2B, OFF_W1, OFF_B1, OFF_W2, OFF_B2};
  const int ns[15]     = {256, 256, 65536, 256, 1024, 1024, 1024, 65536, 256, 256, 256,
                          262144, 1024, 262144, 256};
  for (int i = 0; i < 15; i++) { cd.src[i] = srcs[i]; cd.off[i] = offs[i]; cd.n[i] = ns[i]; }
  cvt_tab<<<dim3(1024, 15), 256, 0, stream>>>(cd, wtab, flagp);
  build_big<<<256, 256, 0, stream>>>(wtab + OFF_WQ, wtab + OFF_WK, Wqbig, Wkbig);
  zero_u16<<<257, 256, 0, stream>>>(KVB, 524544);

  // 1. LN1 stats; xmid = LN1(fx) @ Wx^T + bx -> xm
  ln_stats<<<16384, 256, 0, stream>>>(fx, flagp, 1, mu1, rs1);
  gemm_bt_ln<<<dim3(512, 2), 256, 0, stream>>>(fx, flagp, 1, mu1, rs1,
      wtab + OFF_LN1W, wtab + OFF_LN1B, wtab + OFF_WX, wtab + OFF_BX,
      xm, 256, 256, 0);

  // 2. E2d = exp(xmid @ Wkbig^T) -> xup
  gemm_bt<<<dim3(512, 2), 256, 0, stream>>>(xm, Wkbig, zbias, nullptr, flagp,
                                            xup, 256, 256, 2, 0, 0);

  // 3. G partials + reduce; kv -> KVB block-diag
  accumG<<<256, 256, 0, stream>>>(xm, xup, Gp);
  reduceG<<<264, 256, 0, stream>>>(Gp, Gfin);
  kv_build<<<8, 256, 0, stream>>>(Gfin, wtab + OFF_WV, KVB);

  // 4. Qs = segsoftmax(xmid @ Wqbig^T) -> xup (E2d dead), fused in epilogue
  gemm_bt<<<dim3(512, 2), 256, 0, stream>>>(xm, Wqbig, zbias, nullptr, flagp,
                                            xup, 256, 256, 3, 0, 0);

  // 5. qkv2d = Qs @ KVB[b]^T -> xm (xmid dead), z-batched over b
  gemm_bt<<<dim3(64, 2, 8), 256, 0, stream>>>(xup, KVB, zbias, nullptr, flagp,
                                              xm, 256, 256, 0, 8192, 65536);

  // 6. h = qkv2d @ Wo^T + bo + fx -> xup (Qs dead; NOT in-place -> full grid)
  gemm_bt<<<dim3(512, 2), 256, 0, stream>>>(xm, wtab + OFF_WO, wtab + OFF_BO, fx, flagp,
                                            xup, 256, 256, 0, 0, 0);

  // 7. LN2 stats on h; copy h rows [32768,65536) -> ws hid area (Gp dead).
  //    Launch 1 (rows<32768) writes only dead xm bytes; launch 2 reads only
  //    the copy -> no write-order hazard anywhere.
  ln_stats<<<16384, 256, 0, stream>>>(xup, flagp, 0, mu2, rs2);
  copy_h0<<<4096, 256, 0, stream>>>(xup + (size_t)32768 * 256, hid);

  // 8. fused MLP: y = GELU(LN2(h)@W1^T+b1)@W2^T + b2 + h
  fused_mlp<<<512, 256, 0, stream>>>(xup, mu2, rs2,
      wtab + OFF_LN2W, wtab + OFF_LN2B, wtab + OFF_W1, wtab + OFF_B1,
      wtab + OFF_W2, wtab + OFF_B2, d_out, flagp, 0L);
  fused_mlp<<<512, 256, 0, stream>>>(hid, mu2 + 32768, rs2 + 32768,
      wtab + OFF_LN2W, wtab + OFF_LN2B, wtab + OFF_W1, wtab + OFF_B1,
      wtab + OFF_W2, wtab + OFF_B2, d_out, flagp, 32768L);
}